// Round 11
// baseline (303.684 us; speedup 1.0000x reference)
//
#include <hip/hip_runtime.h>
#include <hip/hip_bf16.h>

#define TT 2048
#define DM 2048
#define NH 16
#define KVH 4
#define HD 128

typedef __attribute__((ext_vector_type(8))) short bs8;
typedef __attribute__((ext_vector_type(4))) float fx4;
typedef __attribute__((ext_vector_type(4))) unsigned short us4;
typedef __attribute__((ext_vector_type(8))) unsigned short us8;

#if __has_builtin(__builtin_amdgcn_exp2f)
#define EXP2(x) __builtin_amdgcn_exp2f(x)
#else
#define EXP2(x) exp2f(x)
#endif

__device__ inline unsigned short f2b(float f) {
  __hip_bfloat16 h = __float2bfloat16(f);
  return *reinterpret_cast<unsigned short*>(&h);
}

__device__ inline float b2f(unsigned short u) {
  unsigned int v = ((unsigned int)u) << 16;
  return *reinterpret_cast<float*>(&v);
}

__device__ inline void gld_lds16(const ushort* g, ushort* l) {
  __builtin_amdgcn_global_load_lds(
      (const __attribute__((address_space(1))) void*)g,
      (__attribute__((address_space(3))) void*)l,
      16, 0, 0);
}

// ---------------- prep: weight transposes + x cast, one dispatch ----------------
// z=0: Wqkvt[3072][2048] from Wq|Wk|Wv   z=1: Wot[2048][2048] from Wo
// z=2: x fp32 -> bf16 cast (linear)
__global__ __launch_bounds__(256) void prep_kernel(
    const float* __restrict__ x, const float* __restrict__ Wq,
    const float* __restrict__ Wk, const float* __restrict__ Wv,
    const float* __restrict__ Wo, ushort* __restrict__ xb,
    ushort* __restrict__ Wqkvt, ushort* __restrict__ Wot) {
  int tx = threadIdx.x, ty = threadIdx.y;  // block (32,8)
  if (blockIdx.z == 2) {
    int lin = (blockIdx.y * 96 + blockIdx.x) * 256 + ty * 32 + tx;
#pragma unroll
    for (int it = 0; it < 2; ++it) {
      int i = lin + it * (6144 * 256);
      if (i < (TT * 2 * DM) / 4) {
        float4 v = ((const float4*)x)[i];
        us4 o = {f2b(v.x), f2b(v.y), f2b(v.z), f2b(v.w)};
        ((us4*)xb)[i] = o;
      }
    }
    return;
  }
  __shared__ float t[32][33];
  int n0 = blockIdx.x * 32, k0 = blockIdx.y * 32;
  if (blockIdx.z == 0) {
    const float* src;
    int srcN, col0;
    if (n0 < 2048) { src = Wq; srcN = 2048; col0 = n0; }
    else if (n0 < 2560) { src = Wk; srcN = 512; col0 = n0 - 2048; }
    else { src = Wv; srcN = 512; col0 = n0 - 2560; }
    for (int jj = 0; jj < 4; ++jj)
      t[ty + jj * 8][tx] = src[(size_t)(k0 + ty + jj * 8) * srcN + col0 + tx];
    __syncthreads();
    for (int jj = 0; jj < 4; ++jj)
      Wqkvt[(size_t)(n0 + ty + jj * 8) * 2048 + k0 + tx] = f2b(t[tx][ty + jj * 8]);
  } else {
    if (n0 >= 2048) return;
    for (int jj = 0; jj < 4; ++jj)
      t[ty + jj * 8][tx] = Wo[(size_t)(k0 + ty + jj * 8) * 2048 + n0 + tx];
    __syncthreads();
    for (int jj = 0; jj < 4; ++jj)
      Wot[(size_t)(n0 + ty + jj * 8) * 2048 + k0 + tx] = f2b(t[tx][ty + jj * 8]);
  }
}

// ---------------- fused QKV GEMM: [4096 x 3072] = xb * Wqkvt^T ----------------
// 256x256 tile, BK=64, 8 waves, 128 KB LDS double-buffer.
// Counted-vmcnt schedule (attn-proven T4): issue tile kt+1's 8 DMAs, then
// vmcnt(8) — tile kt's loads landed, kt+1's stay IN FLIGHT through the whole
// compute phase (the r9 version wrongly drained vmcnt(0) after compute).
#define EPI_STRIDE 136  // shorts; row stride for 128-col epilogue passes
#define VT_STRIDE 264   // shorts; d-row stride for transposed V passes (528 B)
__global__ __launch_bounds__(512, 2) void gemm_qkv(const ushort* __restrict__ A,
                                                   const ushort* __restrict__ Bt,
                                                   ushort* __restrict__ qo,
                                                   ushort* __restrict__ ko,
                                                   ushort* __restrict__ vo,
                                                   int K) {
  __shared__ alignas(16) ushort smem[65536];  // 128 KB
  // As buf c: smem + c*16384 ; Bs buf c: smem + 32768 + c*16384
  const int tid = threadIdx.x;
  const int lane = tid & 63;
  const int wid = tid >> 6;        // 0..7
  const int wm = wid >> 2;         // 0..1  (output row half)
  const int wn = wid & 3;          // 0..3  (output col quarter)
  const int quad = lane >> 4, l16 = lane & 15;
  const int swl = l16 & 7;
  const int bm = blockIdx.y * 256, bn = blockIdx.x * 256;
  const int r8 = lane >> 3, s8 = lane & 7;
  const int cst = s8 ^ r8;         // staging chunk swizzle (m&7 == r8)

  fx4 acc[8][4];
#pragma unroll
  for (int i = 0; i < 8; ++i)
#pragma unroll
    for (int j = 0; j < 4; ++j) acc[i][j] = (fx4){0.f, 0.f, 0.f, 0.f};

  // per-thread staging base pointers (stripe s adds s*64 rows)
  const ushort* apA = A + (size_t)(bm + wid * 8 + r8) * K + cst * 8;
  const ushort* apB = Bt + (size_t)(bn + wid * 8 + r8) * K + cst * 8;
  const int dofs = (wid * 8) * 64;  // LDS dest offset within buffer (lane adds 16B)

  // ---- prologue: stage tile 0 into buf 0 (no wait — counted wait in-loop) ----
#pragma unroll
  for (int s = 0; s < 4; ++s) {
    gld_lds16(apA + (size_t)(s * 64) * K, smem + dofs + s * 4096);
    gld_lds16(apB + (size_t)(s * 64) * K, smem + 32768 + dofs + s * 4096);
  }

  const int NT = K >> 6;
  for (int kt = 0; kt < NT; ++kt) {
    const int cur = kt & 1, nxt = cur ^ 1;
    const ushort* As = smem + cur * 16384;
    const ushort* Bs = smem + 32768 + cur * 16384;
    if (kt + 1 < NT) {
      const ushort* sa = apA + (kt + 1) * 64;
      const ushort* sb = apB + (kt + 1) * 64;
      ushort* dA = smem + nxt * 16384 + dofs;
      ushort* dB = smem + 32768 + nxt * 16384 + dofs;
#pragma unroll
      for (int s = 0; s < 4; ++s) {
        gld_lds16(sa + (size_t)(s * 64) * K, dA + s * 4096);
        gld_lds16(sb + (size_t)(s * 64) * K, dB + s * 4096);
      }
      asm volatile("s_waitcnt vmcnt(8)" ::: "memory");  // kt landed, kt+1 in flight
    } else {
      asm volatile("s_waitcnt vmcnt(0)" ::: "memory");
    }
    __builtin_amdgcn_s_barrier();

#pragma unroll
    for (int p = 0; p < 4; ++p) {
      const int ks = p >> 1, mh = p & 1;
      const int so = (((ks * 4 + quad) ^ swl) << 3);  // swizzled 16B slot (shorts)
      bs8 bf[4], af[4];
#pragma unroll
      for (int nt = 0; nt < 4; ++nt) {
        int n = wn * 64 + nt * 16 + l16;
        bf[nt] = *(const bs8*)(Bs + n * 64 + so);
      }
#pragma unroll
      for (int i = 0; i < 4; ++i) {
        int m = wm * 128 + (mh * 4 + i) * 16 + l16;
        af[i] = *(const bs8*)(As + m * 64 + so);
      }
      __builtin_amdgcn_s_setprio(1);
#pragma unroll
      for (int i = 0; i < 4; ++i)
#pragma unroll
        for (int nt = 0; nt < 4; ++nt)
          acc[mh * 4 + i][nt] = __builtin_amdgcn_mfma_f32_16x16x32_bf16(
              af[i], bf[nt], acc[mh * 4 + i][nt], 0, 0, 0);
      __builtin_amdgcn_s_setprio(0);
    }
    asm volatile("s_waitcnt lgkmcnt(0)" ::: "memory");  // my reads of cur done
    __builtin_amdgcn_s_barrier();                       // license overwrite of cur
  }

  // ---- epilogue: two 128-column passes through LDS ----
  if (bn < 2560) {
    // q / k: row-major [256][136] per pass
#pragma unroll
    for (int h = 0; h < 2; ++h) {
      if ((wn >> 1) == h) {
#pragma unroll
        for (int mt = 0; mt < 8; ++mt)
#pragma unroll
          for (int nt = 0; nt < 4; ++nt)
#pragma unroll
            for (int r = 0; r < 4; ++r) {
              int row = wm * 128 + mt * 16 + quad * 4 + r;      // 0..255
              int col = (wn & 1) * 64 + nt * 16 + l16;          // 0..127
              smem[row * EPI_STRIDE + col] = f2b(acc[mt][nt][r]);
            }
      }
      __builtin_amdgcn_s_barrier();
      const int rsel = tid >> 4;   // 0..31
      const int csel = tid & 15;   // 16B chunk
      for (int ii = 0; ii < 8; ++ii) {
        int row = ii * 32 + rsel;
        us8 chunk = *(const us8*)(smem + row * EPI_STRIDE + csel * 8);
        int row_g = bm + row;
        int colc = bn + h * 128 + csel * 8;
        if (bn < 2048) {
          *(us8*)(qo + (size_t)row_g * 2048 + colc) = chunk;
        } else {
          int b = row_g >> 11, t = row_g & 2047;
          int kc = colc - 2048;
          int gg = kc >> 7, d = kc & 127;
          *(us8*)(ko + ((size_t)(b * KVH + gg) * TT + t) * HD + d) = chunk;
        }
      }
      __builtin_amdgcn_s_barrier();
    }
  } else {
    // V: transposed [d_local 0..127][token 0..255] per pass, stride 264
    const int b = bm >> 11;        // 256-row tile never straddles b (2048%256==0)
    const int t0 = bm & 2047;
#pragma unroll
    for (int h = 0; h < 2; ++h) {
      if ((wn >> 1) == h) {
#pragma unroll
        for (int mt = 0; mt < 8; ++mt)
#pragma unroll
          for (int nt = 0; nt < 4; ++nt)
#pragma unroll
            for (int r = 0; r < 4; ++r) {
              int row = wm * 128 + mt * 16 + quad * 4 + r;      // token_local
              int col = (wn & 1) * 64 + nt * 16 + l16;          // d_local
              smem[col * VT_STRIDE + row] = f2b(acc[mt][nt][r]);
            }
      }
      __builtin_amdgcn_s_barrier();
      const int tc = tid & 31;     // token chunk (8 tokens)
      const int dr = tid >> 5;     // 0..15
      for (int it = 0; it < 8; ++it) {
        int d_local = it * 16 + dr;                        // 0..127
        us8 chunk = *(const us8*)(smem + d_local * VT_STRIDE + tc * 8);
        int vc = (bn - 2560) + h * 128 + d_local;          // 0..511
        int gg = vc >> 7, dd = vc & 127;
        *(us8*)(vo + ((size_t)(b * KVH + gg) * HD + dd) * TT + t0 + tc * 8) = chunk;
      }
      __builtin_amdgcn_s_barrier();
    }
  }
}

// ---------------- output-projection GEMM: fp32 out ----------------
// LDS double-buffer (64 KB; grid 512 = 2 blocks/CU unchanged) + counted-vmcnt
// schedule: issue next tile's 8 DMAs first, vmcnt(8), barrier, compute,
// lgkmcnt(0), barrier. Epilogue overlays the buffers.
__global__ __launch_bounds__(256) void gemm_out(const ushort* __restrict__ A,
                                                const ushort* __restrict__ Bt,
                                                float* __restrict__ Cout,
                                                int N, int K) {
  __shared__ alignas(16) ushort smem[32768];  // 64 KB: buf c at c*16384 (A) / +8192 (B)
  const int tid = threadIdx.x;
  const int lane = tid & 63;
  const int wid = tid >> 6;
  const int wm = wid >> 1, wn = wid & 1;
  const int quad = lane >> 4, l16 = lane & 15;
  const int bm = blockIdx.y * 128, bn = blockIdx.x * 128;

  fx4 acc[4][4];
  for (int i = 0; i < 4; ++i)
    for (int j = 0; j < 4; ++j) acc[i][j] = (fx4){0.f, 0.f, 0.f, 0.f};

  const int r8 = lane >> 3, s8 = lane & 7;
  // per-thread staging addresses: stripe i stages row m = i*32 + wid*8 + r8
  // chunk c = s8 ^ (m&7); m&7 == r8 so c is kt-invariant
  const int cst = s8 ^ r8;
  const ushort* apA = A + (size_t)(bm + wid * 8 + r8) * K + cst * 8;
  const ushort* apB = Bt + (size_t)(bn + wid * 8 + r8) * K + cst * 8;
  const int dofs = (wid * 8) * 64;

  // ---- prologue: stage tile 0 into buf 0 ----
#pragma unroll
  for (int i = 0; i < 4; ++i) {
    gld_lds16(apA + (size_t)(i * 32) * K, smem + dofs + i * 2048);
    gld_lds16(apB + (size_t)(i * 32) * K, smem + 8192 + dofs + i * 2048);
  }

  const int NT = K >> 6;
  for (int kt = 0; kt < NT; ++kt) {
    const int cur = kt & 1, nxt = cur ^ 1;
    const ushort* As = smem + cur * 16384;
    const ushort* Bs = smem + cur * 16384 + 8192;
    if (kt + 1 < NT) {
      const ushort* sa = apA + (kt + 1) * 64;
      const ushort* sb = apB + (kt + 1) * 64;
      ushort* dA = smem + nxt * 16384 + dofs;
      ushort* dB = smem + nxt * 16384 + 8192 + dofs;
#pragma unroll
      for (int i = 0; i < 4; ++i) {
        gld_lds16(sa + (size_t)(i * 32) * K, dA + i * 2048);
        gld_lds16(sb + (size_t)(i * 32) * K, dB + i * 2048);
      }
      asm volatile("s_waitcnt vmcnt(8)" ::: "memory");  // kt landed, kt+1 in flight
    } else {
      asm volatile("s_waitcnt vmcnt(0)" ::: "memory");
    }
    __builtin_amdgcn_s_barrier();

#pragma unroll
    for (int ks = 0; ks < 2; ++ks) {
      bs8 af[4], bf[4];
#pragma unroll
      for (int mt = 0; mt < 4; ++mt) {
        int m = wm * 64 + mt * 16 + l16;
        int c = ks * 4 + quad;
        int slot = c ^ (m & 7);
        af[mt] = *(const bs8*)(As + m * 64 + slot * 8);
      }
#pragma unroll
      for (int nt = 0; nt < 4; ++nt) {
        int n = wn * 64 + nt * 16 + l16;
        int c = ks * 4 + quad;
        int slot = c ^ (n & 7);
        bf[nt] = *(const bs8*)(Bs + n * 64 + slot * 8);
      }
      __builtin_amdgcn_s_setprio(1);
#pragma unroll
      for (int mt = 0; mt < 4; ++mt)
#pragma unroll
        for (int nt = 0; nt < 4; ++nt)
          acc[mt][nt] = __builtin_amdgcn_mfma_f32_16x16x32_bf16(af[mt], bf[nt],
                                                                acc[mt][nt], 0, 0, 0);
      __builtin_amdgcn_s_setprio(0);
    }
    asm volatile("s_waitcnt lgkmcnt(0)" ::: "memory");
    __builtin_amdgcn_s_barrier();
  }

  // ---- epilogue: bf16 LDS round-trip (overlays buffers), fp32 vector stores ----
  for (int mt = 0; mt < 4; ++mt)
    for (int nt = 0; nt < 4; ++nt)
      for (int r = 0; r < 4; ++r) {
        int row = wm * 64 + mt * 16 + quad * 4 + r;
        int col = wn * 64 + nt * 16 + l16;
        smem[row * EPI_STRIDE + col] = f2b(acc[mt][nt][r]);
      }
  __syncthreads();
  const int rsel = tid >> 4;
  const int csel = tid & 15;
  for (int ii = 0; ii < 8; ++ii) {
    int row = ii * 16 + rsel;
    us8 chunk = *(const us8*)(smem + row * EPI_STRIDE + csel * 8);
    int row_g = bm + row;
    int colc = bn + csel * 8;
    float4 lo = {b2f(chunk[0]), b2f(chunk[1]), b2f(chunk[2]), b2f(chunk[3])};
    float4 hi = {b2f(chunk[4]), b2f(chunk[5]), b2f(chunk[6]), b2f(chunk[7])};
    *(float4*)(Cout + (size_t)row_g * N + colc) = lo;
    *(float4*)(Cout + (size_t)row_g * N + colc + 4) = hi;
  }
}

// ---------------- fused causal WGQA attention, 8-wave blocks ----------------
// Verbatim proven 70.5 us version. Ledger: 32q/wave (r2) concurrency-bound;
// V-from-L2 (r3) latency-bound; split-key partials (r5) VGPR spill. Local opt.
__global__ __launch_bounds__(512, 4) void attn_kernel(const ushort* __restrict__ qb,
                                                      const ushort* __restrict__ kb,
                                                      const ushort* __restrict__ vt,
                                                      ushort* __restrict__ yb,
                                                      const float* __restrict__ wlog) {
  __shared__ alignas(16) ushort Ks[2][64 * 128];   // [buf][key][d], chunk-swizzled
  __shared__ alignas(16) ushort Vs[2][128 * 64];   // [buf][d][key], chunk-swizzled
  __shared__ alignas(16) ushort Ps[128 * 64];      // [q][key], chunk-XOR swizzled

  const int bid = blockIdx.x;
  const int qt = (bid & 256) ? (bid & 15) : 15 - (bid & 15);
  const int h = (bid >> 4) & 15;
  const int b = bid >> 8;
  const int g = h >> 2;
  const int tid = threadIdx.x;
  const int lane = tid & 63;
  const int wid = tid >> 6;        // 0..7
  const int quad = lane >> 4;
  const int l16 = lane & 15;
  const int qw = qt * 128 + wid * 16;   // wave's first query

  const float scale = wlog[g] * 0.08838834764831845f;  // 1/sqrt(128)
  const float sc2 = scale * 1.4426950408889634f;       // * log2(e)

  const ushort* kbase = kb + (size_t)(b * KVH + g) * TT * HD;
  const ushort* vbase = vt + (size_t)(b * KVH + g) * HD * TT;

  // persistent staging pointers; each thread stages 2 K-slots + 2 V-slots
  const ushort* kp;
  const ushort* vp;
  {
    int keyr = wid * 4 + (lane >> 4);          // 0..31
    int si = lane & 15;
    int ck = (si & 8) | ((si ^ keyr) & 7);
    kp = kbase + (size_t)keyr * HD + ck * 8;
    int dr = wid * 8 + (lane >> 3);            // 0..63
    int s8 = lane & 7;
    int cv = s8 ^ (dr & 7);
    vp = vbase + (size_t)dr * TT + cv * 8;
  }

  // ---- prologue: stage tile 0 into buffer 0 (DMA runs under Q-load) ----
  gld_lds16(kp, &Ks[0][wid * 512]);
  gld_lds16(kp + 32 * HD, &Ks[0][4096 + wid * 512]);
  gld_lds16(vp, &Vs[0][wid * 512]);
  gld_lds16(vp + 64 * TT, &Vs[0][4096 + wid * 512]);
  kp += 64 * HD;
  vp += 64;

  // Q fragments in registers (B-operand of S^T = K * Q^T)
  bs8 qf[4];
  {
    int q = qw + l16;
    const ushort* qrow = qb + ((size_t)(b * TT + q)) * DM + h * HD;
#pragma unroll
    for (int ks = 0; ks < 4; ++ks)
      qf[ks] = *(const bs8*)(qrow + ks * 32 + quad * 8);
  }

  float m_i = -INFINITY;  // running max of RAW logits
  float l_i = 0.f;
  fx4 o[8];
#pragma unroll
  for (int i = 0; i < 8; ++i) o[i] = (fx4){0.f, 0.f, 0.f, 0.f};

  const int jmax = 2 * qt + 1;
  for (int j = 0; j <= jmax; ++j) {
    const int cur = j & 1;
    // ---- issue NEXT tile's DMAs first, then wait only for tile j ----
    if (j < jmax) {
      const int nxt = cur ^ 1;
      gld_lds16(kp, &Ks[nxt][wid * 512]);
      gld_lds16(kp + 32 * HD, &Ks[nxt][4096 + wid * 512]);
      gld_lds16(vp, &Vs[nxt][wid * 512]);
      gld_lds16(vp + 64 * TT, &Vs[nxt][4096 + wid * 512]);
      kp += 64 * HD;
      vp += 64;
      asm volatile("s_waitcnt vmcnt(4)" ::: "memory");  // tile j done, j+1 in flight
    } else {
      asm volatile("s_waitcnt vmcnt(0)" ::: "memory");
    }
    __builtin_amdgcn_s_barrier();

    if (j * 64 <= qw + 15) {  // wave has at least one unmasked key
      const ushort* Kc = Ks[cur];
      const ushort* Vc = Vs[cur];
      // ---- S^T = K * Q^T  (64 keys x 16 queries), fp32 acc ----
      fx4 s[4];
#pragma unroll
      for (int mt = 0; mt < 4; ++mt) s[mt] = (fx4){0.f, 0.f, 0.f, 0.f};
      __builtin_amdgcn_s_setprio(1);
#pragma unroll
      for (int mt = 0; mt < 4; ++mt) {
        bs8 a[4];
        int key = mt * 16 + l16;
#pragma unroll
        for (int ks = 0; ks < 4; ++ks) {
          int c = ks * 4 + quad;
          int slot = (c & 8) | ((c ^ key) & 7);
          a[ks] = *(const bs8*)(Kc + key * 128 + slot * 8);
        }
#pragma unroll
        for (int ks = 0; ks < 4; ++ks)
          s[mt] = __builtin_amdgcn_mfma_f32_16x16x32_bf16(a[ks], qf[ks],
                                                          s[mt], 0, 0, 0);
      }
      __builtin_amdgcn_s_setprio(0);

      // ---- causal mask: needed iff tile max key > wave min query ----
      const int q = qw + l16;
      if (j * 64 + 63 > qw) {
#pragma unroll
        for (int mt = 0; mt < 4; ++mt)
#pragma unroll
          for (int r = 0; r < 4; ++r) {
            int key = j * 64 + mt * 16 + quad * 4 + r;
            if (key > q) s[mt][r] = -1e30f;
          }
      }
      float mx = s[0][0];
#pragma unroll
      for (int mt = 0; mt < 4; ++mt)
#pragma unroll
        for (int r = 0; r < 4; ++r) mx = fmaxf(mx, s[mt][r]);
      mx = fmaxf(mx, __shfl_xor(mx, 16));
      mx = fmaxf(mx, __shfl_xor(mx, 32));

      // ---- defer-max: only rescale when the max actually grows (>8 scaled) ----
      if (!__all((mx - m_i) * scale <= 8.0f)) {
        float m_new = fmaxf(m_i, mx);
        float alpha = EXP2((m_i - m_new) * sc2);
        l_i *= alpha;
#pragma unroll
        for (int dmt = 0; dmt < 8; ++dmt)
#pragma unroll
          for (int r = 0; r < 4; ++r) o[dmt][r] *= alpha;
        m_i = m_new;
      }
      float negb = -m_i * sc2;
      float sum = 0.f;
#pragma unroll
      for (int mt = 0; mt < 4; ++mt)
#pragma unroll
        for (int r = 0; r < 4; ++r) {
          float pv = EXP2(fmaf(s[mt][r], sc2, negb));
          s[mt][r] = pv;
          sum += pv;
        }
      sum += __shfl_xor(sum, 16);
      sum += __shfl_xor(sum, 32);
      l_i += sum;

      // P (bf16) to LDS, [q][key] stride 64 with chunk-XOR swizzle;
      // wave touches only its own 16 rows -> no barrier needed
      int qrow = wid * 16 + l16;
      int sw = l16 & 7;
#pragma unroll
      for (int mt = 0; mt < 4; ++mt) {
        us4 pw = {f2b(s[mt][0]), f2b(s[mt][1]), f2b(s[mt][2]), f2b(s[mt][3])};
        int chunk = mt * 2 + (quad >> 1);
        *(us4*)(Ps + qrow * 64 + ((chunk ^ sw) << 3) + ((quad & 1) << 2)) = pw;
      }

      // ---- O^T += V^T * P^T  (no barrier: wave reads only its own P rows) ----
#pragma unroll
      for (int ks = 0; ks < 2; ++ks) {
        bs8 pb = *(const bs8*)(Ps + qrow * 64 + (((ks * 4 + quad) ^ sw) << 3));
        __builtin_amdgcn_s_setprio(1);
#pragma unroll
        for (int dmt = 0; dmt < 8; ++dmt) {
          int d = dmt * 16 + l16;
          int c = ks * 4 + quad;
          int slot = c ^ (d & 7);
          bs8 va = *(const bs8*)(Vc + d * 64 + slot * 8);
          o[dmt] = __builtin_amdgcn_mfma_f32_16x16x32_bf16(va, pb, o[dmt], 0, 0, 0);
        }
        __builtin_amdgcn_s_setprio(0);
      }
    }
    // all my LDS reads of buf[cur] must be complete before signaling; the
    // barrier then licenses other waves' DMAs for tile j+2 to overwrite it
    asm volatile("s_waitcnt lgkmcnt(0)" ::: "memory");
    __builtin_amdgcn_s_barrier();
  }

  // ---- epilogue: normalize and write y (bf16, [b][t][h*128+d]) ----
  {
    float inv = 1.0f / l_i;
    int q = qw + l16;
    ushort* yrow = yb + ((size_t)(b * TT + q)) * DM + h * HD;
#pragma unroll
    for (int dmt = 0; dmt < 8; ++dmt) {
      us4 w = {f2b(o[dmt][0] * inv), f2b(o[dmt][1] * inv),
               f2b(o[dmt][2] * inv), f2b(o[dmt][3] * inv)};
      *(us4*)(yrow + dmt * 16 + quad * 4) = w;
    }
  }
}

// ---------------- launch ----------------
extern "C" void kernel_launch(void* const* d_in, const int* in_sizes, int n_in,
                              void* d_out, int out_size, void* d_ws, size_t ws_size,
                              hipStream_t stream) {
  const float* x = (const float*)d_in[0];
  // d_in[1] = attn_mask: ignored (exact causal mask computed analytically)
  const float* Wq = (const float*)d_in[2];
  const float* Wk = (const float*)d_in[3];
  const float* Wv = (const float*)d_in[4];
  const float* Wo = (const float*)d_in[5];
  const float* wlog = (const float*)d_in[6];
  // d_in[7] = weight_values: unused by the reference

  char* ws = (char*)d_ws;
  ushort* xb = (ushort*)ws;     ws += (size_t)4096 * 2048 * 2;
  ushort* Wqkvt = (ushort*)ws;  ws += (size_t)3072 * 2048 * 2;
  ushort* Wot = (ushort*)ws;    ws += (size_t)2048 * 2048 * 2;
  ushort* qbuf = (ushort*)ws;   ws += (size_t)4096 * 2048 * 2;
  ushort* kbuf = (ushort*)ws;   ws += (size_t)2 * KVH * 2048 * 128 * 2;
  ushort* vbuf = (ushort*)ws;   ws += (size_t)2 * KVH * 2048 * 128 * 2;
  ushort* ybuf = (ushort*)ws;   ws += (size_t)4096 * 2048 * 2;

  prep_kernel<<<dim3(96, 64, 3), dim3(32, 8), 0, stream>>>(
      x, Wq, Wk, Wv, Wo, xb, Wqkvt, Wot);
  gemm_qkv<<<dim3(12, 16), 512, 0, stream>>>(xb, Wqkvt, qbuf, kbuf, vbuf, 2048);
  attn_kernel<<<512, 512, 0, stream>>>(qbuf, kbuf, vbuf, ybuf, wlog);
  gemm_out<<<dim3(16, 32), 256, 0, stream>>>(ybuf, Wot, (float*)d_out, 2048, 2048);
}

// Round 12
// 300.719 us; speedup vs baseline: 1.0099x; 1.0099x over previous
//
#include <hip/hip_runtime.h>
#include <hip/hip_bf16.h>

#define TT 2048
#define DM 2048
#define NH 16
#define KVH 4
#define HD 128

typedef __attribute__((ext_vector_type(8))) short bs8;
typedef __attribute__((ext_vector_type(4))) float fx4;
typedef __attribute__((ext_vector_type(4))) unsigned short us4;
typedef __attribute__((ext_vector_type(8))) unsigned short us8;

#if __has_builtin(__builtin_amdgcn_exp2f)
#define EXP2(x) __builtin_amdgcn_exp2f(x)
#else
#define EXP2(x) exp2f(x)
#endif

__device__ inline unsigned short f2b(float f) {
  __hip_bfloat16 h = __float2bfloat16(f);
  return *reinterpret_cast<unsigned short*>(&h);
}

__device__ inline float b2f(unsigned short u) {
  unsigned int v = ((unsigned int)u) << 16;
  return *reinterpret_cast<float*>(&v);
}

__device__ inline void gld_lds16(const ushort* g, ushort* l) {
  __builtin_amdgcn_global_load_lds(
      (const __attribute__((address_space(1))) void*)g,
      (__attribute__((address_space(3))) void*)l,
      16, 0, 0);
}

// ---------------- prep: weight transposes + x cast, one dispatch ----------------
// z=0: Wqkvt[3072][2048] from Wq|Wk|Wv   z=1: Wot[2048][2048] from Wo
// z=2: x fp32 -> bf16 cast (linear)
__global__ __launch_bounds__(256) void prep_kernel(
    const float* __restrict__ x, const float* __restrict__ Wq,
    const float* __restrict__ Wk, const float* __restrict__ Wv,
    const float* __restrict__ Wo, ushort* __restrict__ xb,
    ushort* __restrict__ Wqkvt, ushort* __restrict__ Wot) {
  int tx = threadIdx.x, ty = threadIdx.y;  // block (32,8)
  if (blockIdx.z == 2) {
    int lin = (blockIdx.y * 96 + blockIdx.x) * 256 + ty * 32 + tx;
#pragma unroll
    for (int it = 0; it < 2; ++it) {
      int i = lin + it * (6144 * 256);
      if (i < (TT * 2 * DM) / 4) {
        float4 v = ((const float4*)x)[i];
        us4 o = {f2b(v.x), f2b(v.y), f2b(v.z), f2b(v.w)};
        ((us4*)xb)[i] = o;
      }
    }
    return;
  }
  __shared__ float t[32][33];
  int n0 = blockIdx.x * 32, k0 = blockIdx.y * 32;
  if (blockIdx.z == 0) {
    const float* src;
    int srcN, col0;
    if (n0 < 2048) { src = Wq; srcN = 2048; col0 = n0; }
    else if (n0 < 2560) { src = Wk; srcN = 512; col0 = n0 - 2048; }
    else { src = Wv; srcN = 512; col0 = n0 - 2560; }
    for (int jj = 0; jj < 4; ++jj)
      t[ty + jj * 8][tx] = src[(size_t)(k0 + ty + jj * 8) * srcN + col0 + tx];
    __syncthreads();
    for (int jj = 0; jj < 4; ++jj)
      Wqkvt[(size_t)(n0 + ty + jj * 8) * 2048 + k0 + tx] = f2b(t[tx][ty + jj * 8]);
  } else {
    if (n0 >= 2048) return;
    for (int jj = 0; jj < 4; ++jj)
      t[ty + jj * 8][tx] = Wo[(size_t)(k0 + ty + jj * 8) * 2048 + n0 + tx];
    __syncthreads();
    for (int jj = 0; jj < 4; ++jj)
      Wot[(size_t)(n0 + ty + jj * 8) * 2048 + k0 + tx] = f2b(t[tx][ty + jj * 8]);
  }
}

// ---------------- fused QKV GEMM: [4096 x 3072] = xb * Wqkvt^T ----------------
// 256x256 tile, BK=64, 8 waves, 128 KB LDS double-buffer.
// Counted-vmcnt schedule (attn-proven T4): issue tile kt+1's 8 DMAs, then
// vmcnt(8) — tile kt's loads landed, kt+1's stay IN FLIGHT through the whole
// compute phase. (r11: verified — dispatch left the top-5, ~78 -> <70 us.)
#define EPI_STRIDE 136  // shorts; row stride for 128-col epilogue passes
#define VT_STRIDE 264   // shorts; d-row stride for transposed V passes (528 B)
__global__ __launch_bounds__(512, 2) void gemm_qkv(const ushort* __restrict__ A,
                                                   const ushort* __restrict__ Bt,
                                                   ushort* __restrict__ qo,
                                                   ushort* __restrict__ ko,
                                                   ushort* __restrict__ vo,
                                                   int K) {
  __shared__ alignas(16) ushort smem[65536];  // 128 KB
  // As buf c: smem + c*16384 ; Bs buf c: smem + 32768 + c*16384
  const int tid = threadIdx.x;
  const int lane = tid & 63;
  const int wid = tid >> 6;        // 0..7
  const int wm = wid >> 2;         // 0..1  (output row half)
  const int wn = wid & 3;          // 0..3  (output col quarter)
  const int quad = lane >> 4, l16 = lane & 15;
  const int swl = l16 & 7;
  const int bm = blockIdx.y * 256, bn = blockIdx.x * 256;
  const int r8 = lane >> 3, s8 = lane & 7;
  const int cst = s8 ^ r8;         // staging chunk swizzle (m&7 == r8)

  fx4 acc[8][4];
#pragma unroll
  for (int i = 0; i < 8; ++i)
#pragma unroll
    for (int j = 0; j < 4; ++j) acc[i][j] = (fx4){0.f, 0.f, 0.f, 0.f};

  // per-thread staging base pointers (stripe s adds s*64 rows)
  const ushort* apA = A + (size_t)(bm + wid * 8 + r8) * K + cst * 8;
  const ushort* apB = Bt + (size_t)(bn + wid * 8 + r8) * K + cst * 8;
  const int dofs = (wid * 8) * 64;  // LDS dest offset within buffer (lane adds 16B)

  // ---- prologue: stage tile 0 into buf 0 (no wait — counted wait in-loop) ----
#pragma unroll
  for (int s = 0; s < 4; ++s) {
    gld_lds16(apA + (size_t)(s * 64) * K, smem + dofs + s * 4096);
    gld_lds16(apB + (size_t)(s * 64) * K, smem + 32768 + dofs + s * 4096);
  }

  const int NT = K >> 6;
  for (int kt = 0; kt < NT; ++kt) {
    const int cur = kt & 1, nxt = cur ^ 1;
    const ushort* As = smem + cur * 16384;
    const ushort* Bs = smem + 32768 + cur * 16384;
    if (kt + 1 < NT) {
      const ushort* sa = apA + (kt + 1) * 64;
      const ushort* sb = apB + (kt + 1) * 64;
      ushort* dA = smem + nxt * 16384 + dofs;
      ushort* dB = smem + 32768 + nxt * 16384 + dofs;
#pragma unroll
      for (int s = 0; s < 4; ++s) {
        gld_lds16(sa + (size_t)(s * 64) * K, dA + s * 4096);
        gld_lds16(sb + (size_t)(s * 64) * K, dB + s * 4096);
      }
      asm volatile("s_waitcnt vmcnt(8)" ::: "memory");  // kt landed, kt+1 in flight
    } else {
      asm volatile("s_waitcnt vmcnt(0)" ::: "memory");
    }
    __builtin_amdgcn_s_barrier();

#pragma unroll
    for (int p = 0; p < 4; ++p) {
      const int ks = p >> 1, mh = p & 1;
      const int so = (((ks * 4 + quad) ^ swl) << 3);  // swizzled 16B slot (shorts)
      bs8 bf[4], af[4];
#pragma unroll
      for (int nt = 0; nt < 4; ++nt) {
        int n = wn * 64 + nt * 16 + l16;
        bf[nt] = *(const bs8*)(Bs + n * 64 + so);
      }
#pragma unroll
      for (int i = 0; i < 4; ++i) {
        int m = wm * 128 + (mh * 4 + i) * 16 + l16;
        af[i] = *(const bs8*)(As + m * 64 + so);
      }
      __builtin_amdgcn_s_setprio(1);
#pragma unroll
      for (int i = 0; i < 4; ++i)
#pragma unroll
        for (int nt = 0; nt < 4; ++nt)
          acc[mh * 4 + i][nt] = __builtin_amdgcn_mfma_f32_16x16x32_bf16(
              af[i], bf[nt], acc[mh * 4 + i][nt], 0, 0, 0);
      __builtin_amdgcn_s_setprio(0);
    }
    asm volatile("s_waitcnt lgkmcnt(0)" ::: "memory");  // my reads of cur done
    __builtin_amdgcn_s_barrier();                       // license overwrite of cur
  }

  // ---- epilogue: two 128-column passes through LDS ----
  if (bn < 2560) {
    // q / k: row-major [256][136] per pass
#pragma unroll
    for (int h = 0; h < 2; ++h) {
      if ((wn >> 1) == h) {
#pragma unroll
        for (int mt = 0; mt < 8; ++mt)
#pragma unroll
          for (int nt = 0; nt < 4; ++nt)
#pragma unroll
            for (int r = 0; r < 4; ++r) {
              int row = wm * 128 + mt * 16 + quad * 4 + r;      // 0..255
              int col = (wn & 1) * 64 + nt * 16 + l16;          // 0..127
              smem[row * EPI_STRIDE + col] = f2b(acc[mt][nt][r]);
            }
      }
      __builtin_amdgcn_s_barrier();
      const int rsel = tid >> 4;   // 0..31
      const int csel = tid & 15;   // 16B chunk
      for (int ii = 0; ii < 8; ++ii) {
        int row = ii * 32 + rsel;
        us8 chunk = *(const us8*)(smem + row * EPI_STRIDE + csel * 8);
        int row_g = bm + row;
        int colc = bn + h * 128 + csel * 8;
        if (bn < 2048) {
          *(us8*)(qo + (size_t)row_g * 2048 + colc) = chunk;
        } else {
          int b = row_g >> 11, t = row_g & 2047;
          int kc = colc - 2048;
          int gg = kc >> 7, d = kc & 127;
          *(us8*)(ko + ((size_t)(b * KVH + gg) * TT + t) * HD + d) = chunk;
        }
      }
      __builtin_amdgcn_s_barrier();
    }
  } else {
    // V: transposed [d_local 0..127][token 0..255] per pass, stride 264
    const int b = bm >> 11;        // 256-row tile never straddles b (2048%256==0)
    const int t0 = bm & 2047;
#pragma unroll
    for (int h = 0; h < 2; ++h) {
      if ((wn >> 1) == h) {
#pragma unroll
        for (int mt = 0; mt < 8; ++mt)
#pragma unroll
          for (int nt = 0; nt < 4; ++nt)
#pragma unroll
            for (int r = 0; r < 4; ++r) {
              int row = wm * 128 + mt * 16 + quad * 4 + r;      // token_local
              int col = (wn & 1) * 64 + nt * 16 + l16;          // d_local
              smem[col * VT_STRIDE + row] = f2b(acc[mt][nt][r]);
            }
      }
      __builtin_amdgcn_s_barrier();
      const int tc = tid & 31;     // token chunk (8 tokens)
      const int dr = tid >> 5;     // 0..15
      for (int it = 0; it < 8; ++it) {
        int d_local = it * 16 + dr;                        // 0..127
        us8 chunk = *(const us8*)(smem + d_local * VT_STRIDE + tc * 8);
        int vc = (bn - 2560) + h * 128 + d_local;          // 0..511
        int gg = vc >> 7, dd = vc & 127;
        *(us8*)(vo + ((size_t)(b * KVH + gg) * HD + dd) * TT + t0 + tc * 8) = chunk;
      }
      __builtin_amdgcn_s_barrier();
    }
  }
}

// ---------------- output-projection GEMM: fp32 out ----------------
// ROUND-12: 256x128 tile on the proven counted-vmcnt template. Grid (16,16) =
// 256 blocks = exactly 1 block/CU at 100% fill (gemm_qkv's 256^2 is stuck at
// 75%). 8 waves (wave owns 64x64, acc[4][4] — no spill risk); 96 KB LDS dbuf;
// 6 DMAs/thread/K-step (4A+2B); issue-next-first + vmcnt(6); A-panel staged
// once per 256 output rows (2x arithmetic intensity on A vs 128^2).
__global__ __launch_bounds__(512, 2) void gemm_out(const ushort* __restrict__ A,
                                                   const ushort* __restrict__ Bt,
                                                   float* __restrict__ Cout,
                                                   int N, int K) {
  __shared__ alignas(16) ushort smem[49152];  // 96 KB
  // A buf c: smem + c*16384 (256x64) ; B buf c: smem + 32768 + c*8192 (128x64)
  const int tid = threadIdx.x;
  const int lane = tid & 63;
  const int wid = tid >> 6;        // 0..7
  const int wm = wid >> 1;         // 0..3 (64-row band of 256)
  const int wn = wid & 1;          // 0..1 (64-col half of 128)
  const int quad = lane >> 4, l16 = lane & 15;
  const int swl = l16 & 7;
  const int bm = blockIdx.y * 256, bn = blockIdx.x * 128;
  const int r8 = lane >> 3, s8 = lane & 7;
  const int cst = s8 ^ r8;         // staging chunk swizzle (m&7 == r8)

  fx4 acc[4][4];
#pragma unroll
  for (int i = 0; i < 4; ++i)
#pragma unroll
    for (int j = 0; j < 4; ++j) acc[i][j] = (fx4){0.f, 0.f, 0.f, 0.f};

  const ushort* apA = A + (size_t)(bm + wid * 8 + r8) * K + cst * 8;
  const ushort* apB = Bt + (size_t)(bn + wid * 8 + r8) * K + cst * 8;
  const int dofs = (wid * 8) * 64;

  // ---- prologue: stage tile 0 into buf 0 (counted wait in-loop) ----
#pragma unroll
  for (int s = 0; s < 4; ++s)
    gld_lds16(apA + (size_t)(s * 64) * K, smem + dofs + s * 4096);
#pragma unroll
  for (int s = 0; s < 2; ++s)
    gld_lds16(apB + (size_t)(s * 64) * K, smem + 32768 + dofs + s * 4096);

  const int NT = K >> 6;
  for (int kt = 0; kt < NT; ++kt) {
    const int cur = kt & 1, nxt = cur ^ 1;
    const ushort* As = smem + cur * 16384;
    const ushort* Bs = smem + 32768 + cur * 8192;
    if (kt + 1 < NT) {
      const ushort* sa = apA + (kt + 1) * 64;
      const ushort* sb = apB + (kt + 1) * 64;
      ushort* dA = smem + nxt * 16384 + dofs;
      ushort* dB = smem + 32768 + nxt * 8192 + dofs;
#pragma unroll
      for (int s = 0; s < 4; ++s)
        gld_lds16(sa + (size_t)(s * 64) * K, dA + s * 4096);
#pragma unroll
      for (int s = 0; s < 2; ++s)
        gld_lds16(sb + (size_t)(s * 64) * K, dB + s * 4096);
      asm volatile("s_waitcnt vmcnt(6)" ::: "memory");  // kt landed, kt+1 in flight
    } else {
      asm volatile("s_waitcnt vmcnt(0)" ::: "memory");
    }
    __builtin_amdgcn_s_barrier();

#pragma unroll
    for (int ks = 0; ks < 2; ++ks) {
      const int so = (((ks * 4 + quad) ^ swl) << 3);
      bs8 af[4], bf[4];
#pragma unroll
      for (int mt = 0; mt < 4; ++mt) {
        int m = wm * 64 + mt * 16 + l16;
        af[mt] = *(const bs8*)(As + m * 64 + so);
      }
#pragma unroll
      for (int nt = 0; nt < 4; ++nt) {
        int n = wn * 64 + nt * 16 + l16;
        bf[nt] = *(const bs8*)(Bs + n * 64 + so);
      }
      __builtin_amdgcn_s_setprio(1);
#pragma unroll
      for (int mt = 0; mt < 4; ++mt)
#pragma unroll
        for (int nt = 0; nt < 4; ++nt)
          acc[mt][nt] = __builtin_amdgcn_mfma_f32_16x16x32_bf16(af[mt], bf[nt],
                                                                acc[mt][nt], 0, 0, 0);
      __builtin_amdgcn_s_setprio(0);
    }
    asm volatile("s_waitcnt lgkmcnt(0)" ::: "memory");
    __builtin_amdgcn_s_barrier();
  }

  // ---- epilogue: bf16 LDS round-trip [256][136] (overlays buffers) ----
  for (int mt = 0; mt < 4; ++mt)
    for (int nt = 0; nt < 4; ++nt)
      for (int r = 0; r < 4; ++r) {
        int row = wm * 64 + mt * 16 + quad * 4 + r;   // 0..255
        int col = wn * 64 + nt * 16 + l16;            // 0..127
        smem[row * EPI_STRIDE + col] = f2b(acc[mt][nt][r]);
      }
  __syncthreads();
  const int rsel = tid >> 4;   // 0..31
  const int csel = tid & 15;   // 16B chunk
  for (int ii = 0; ii < 8; ++ii) {
    int row = ii * 32 + rsel;
    us8 chunk = *(const us8*)(smem + row * EPI_STRIDE + csel * 8);
    int row_g = bm + row;
    int colc = bn + csel * 8;
    float4 lo = {b2f(chunk[0]), b2f(chunk[1]), b2f(chunk[2]), b2f(chunk[3])};
    float4 hi = {b2f(chunk[4]), b2f(chunk[5]), b2f(chunk[6]), b2f(chunk[7])};
    *(float4*)(Cout + (size_t)row_g * N + colc) = lo;
    *(float4*)(Cout + (size_t)row_g * N + colc + 4) = hi;
  }
}

// ---------------- fused causal WGQA attention, 8-wave blocks ----------------
// Verbatim proven 70.5 us version. Ledger: 32q/wave (r2) concurrency-bound;
// V-from-L2 (r3) latency-bound; split-key partials (r5) VGPR spill. Local opt.
__global__ __launch_bounds__(512, 4) void attn_kernel(const ushort* __restrict__ qb,
                                                      const ushort* __restrict__ kb,
                                                      const ushort* __restrict__ vt,
                                                      ushort* __restrict__ yb,
                                                      const float* __restrict__ wlog) {
  __shared__ alignas(16) ushort Ks[2][64 * 128];   // [buf][key][d], chunk-swizzled
  __shared__ alignas(16) ushort Vs[2][128 * 64];   // [buf][d][key], chunk-swizzled
  __shared__ alignas(16) ushort Ps[128 * 64];      // [q][key], chunk-XOR swizzled

  const int bid = blockIdx.x;
  const int qt = (bid & 256) ? (bid & 15) : 15 - (bid & 15);
  const int h = (bid >> 4) & 15;
  const int b = bid >> 8;
  const int g = h >> 2;
  const int tid = threadIdx.x;
  const int lane = tid & 63;
  const int wid = tid >> 6;        // 0..7
  const int quad = lane >> 4;
  const int l16 = lane & 15;
  const int qw = qt * 128 + wid * 16;   // wave's first query

  const float scale = wlog[g] * 0.08838834764831845f;  // 1/sqrt(128)
  const float sc2 = scale * 1.4426950408889634f;       // * log2(e)

  const ushort* kbase = kb + (size_t)(b * KVH + g) * TT * HD;
  const ushort* vbase = vt + (size_t)(b * KVH + g) * HD * TT;

  // persistent staging pointers; each thread stages 2 K-slots + 2 V-slots
  const ushort* kp;
  const ushort* vp;
  {
    int keyr = wid * 4 + (lane >> 4);          // 0..31
    int si = lane & 15;
    int ck = (si & 8) | ((si ^ keyr) & 7);
    kp = kbase + (size_t)keyr * HD + ck * 8;
    int dr = wid * 8 + (lane >> 3);            // 0..63
    int s8 = lane & 7;
    int cv = s8 ^ (dr & 7);
    vp = vbase + (size_t)dr * TT + cv * 8;
  }

  // ---- prologue: stage tile 0 into buffer 0 (DMA runs under Q-load) ----
  gld_lds16(kp, &Ks[0][wid * 512]);
  gld_lds16(kp + 32 * HD, &Ks[0][4096 + wid * 512]);
  gld_lds16(vp, &Vs[0][wid * 512]);
  gld_lds16(vp + 64 * TT, &Vs[0][4096 + wid * 512]);
  kp += 64 * HD;
  vp += 64;

  // Q fragments in registers (B-operand of S^T = K * Q^T)
  bs8 qf[4];
  {
    int q = qw + l16;
    const ushort* qrow = qb + ((size_t)(b * TT + q)) * DM + h * HD;
#pragma unroll
    for (int ks = 0; ks < 4; ++ks)
      qf[ks] = *(const bs8*)(qrow + ks * 32 + quad * 8);
  }

  float m_i = -INFINITY;  // running max of RAW logits
  float l_i = 0.f;
  fx4 o[8];
#pragma unroll
  for (int i = 0; i < 8; ++i) o[i] = (fx4){0.f, 0.f, 0.f, 0.f};

  const int jmax = 2 * qt + 1;
  for (int j = 0; j <= jmax; ++j) {
    const int cur = j & 1;
    // ---- issue NEXT tile's DMAs first, then wait only for tile j ----
    if (j < jmax) {
      const int nxt = cur ^ 1;
      gld_lds16(kp, &Ks[nxt][wid * 512]);
      gld_lds16(kp + 32 * HD, &Ks[nxt][4096 + wid * 512]);
      gld_lds16(vp, &Vs[nxt][wid * 512]);
      gld_lds16(vp + 64 * TT, &Vs[nxt][4096 + wid * 512]);
      kp += 64 * HD;
      vp += 64;
      asm volatile("s_waitcnt vmcnt(4)" ::: "memory");  // tile j done, j+1 in flight
    } else {
      asm volatile("s_waitcnt vmcnt(0)" ::: "memory");
    }
    __builtin_amdgcn_s_barrier();

    if (j * 64 <= qw + 15) {  // wave has at least one unmasked key
      const ushort* Kc = Ks[cur];
      const ushort* Vc = Vs[cur];
      // ---- S^T = K * Q^T  (64 keys x 16 queries), fp32 acc ----
      fx4 s[4];
#pragma unroll
      for (int mt = 0; mt < 4; ++mt) s[mt] = (fx4){0.f, 0.f, 0.f, 0.f};
      __builtin_amdgcn_s_setprio(1);
#pragma unroll
      for (int mt = 0; mt < 4; ++mt) {
        bs8 a[4];
        int key = mt * 16 + l16;
#pragma unroll
        for (int ks = 0; ks < 4; ++ks) {
          int c = ks * 4 + quad;
          int slot = (c & 8) | ((c ^ key) & 7);
          a[ks] = *(const bs8*)(Kc + key * 128 + slot * 8);
        }
#pragma unroll
        for (int ks = 0; ks < 4; ++ks)
          s[mt] = __builtin_amdgcn_mfma_f32_16x16x32_bf16(a[ks], qf[ks],
                                                          s[mt], 0, 0, 0);
      }
      __builtin_amdgcn_s_setprio(0);

      // ---- causal mask: needed iff tile max key > wave min query ----
      const int q = qw + l16;
      if (j * 64 + 63 > qw) {
#pragma unroll
        for (int mt = 0; mt < 4; ++mt)
#pragma unroll
          for (int r = 0; r < 4; ++r) {
            int key = j * 64 + mt * 16 + quad * 4 + r;
            if (key > q) s[mt][r] = -1e30f;
          }
      }
      float mx = s[0][0];
#pragma unroll
      for (int mt = 0; mt < 4; ++mt)
#pragma unroll
        for (int r = 0; r < 4; ++r) mx = fmaxf(mx, s[mt][r]);
      mx = fmaxf(mx, __shfl_xor(mx, 16));
      mx = fmaxf(mx, __shfl_xor(mx, 32));

      // ---- defer-max: only rescale when the max actually grows (>8 scaled) ----
      if (!__all((mx - m_i) * scale <= 8.0f)) {
        float m_new = fmaxf(m_i, mx);
        float alpha = EXP2((m_i - m_new) * sc2);
        l_i *= alpha;
#pragma unroll
        for (int dmt = 0; dmt < 8; ++dmt)
#pragma unroll
          for (int r = 0; r < 4; ++r) o[dmt][r] *= alpha;
        m_i = m_new;
      }
      float negb = -m_i * sc2;
      float sum = 0.f;
#pragma unroll
      for (int mt = 0; mt < 4; ++mt)
#pragma unroll
        for (int r = 0; r < 4; ++r) {
          float pv = EXP2(fmaf(s[mt][r], sc2, negb));
          s[mt][r] = pv;
          sum += pv;
        }
      sum += __shfl_xor(sum, 16);
      sum += __shfl_xor(sum, 32);
      l_i += sum;

      // P (bf16) to LDS, [q][key] stride 64 with chunk-XOR swizzle;
      // wave touches only its own 16 rows -> no barrier needed
      int qrow = wid * 16 + l16;
      int sw = l16 & 7;
#pragma unroll
      for (int mt = 0; mt < 4; ++mt) {
        us4 pw = {f2b(s[mt][0]), f2b(s[mt][1]), f2b(s[mt][2]), f2b(s[mt][3])};
        int chunk = mt * 2 + (quad >> 1);
        *(us4*)(Ps + qrow * 64 + ((chunk ^ sw) << 3) + ((quad & 1) << 2)) = pw;
      }

      // ---- O^T += V^T * P^T  (no barrier: wave reads only its own P rows) ----
#pragma unroll
      for (int ks = 0; ks < 2; ++ks) {
        bs8 pb = *(const bs8*)(Ps + qrow * 64 + (((ks * 4 + quad) ^ sw) << 3));
        __builtin_amdgcn_s_setprio(1);
#pragma unroll
        for (int dmt = 0; dmt < 8; ++dmt) {
          int d = dmt * 16 + l16;
          int c = ks * 4 + quad;
          int slot = c ^ (d & 7);
          bs8 va = *(const bs8*)(Vc + d * 64 + slot * 8);
          o[dmt] = __builtin_amdgcn_mfma_f32_16x16x32_bf16(va, pb, o[dmt], 0, 0, 0);
        }
        __builtin_amdgcn_s_setprio(0);
      }
    }
    // all my LDS reads of buf[cur] must be complete before signaling; the
    // barrier then licenses other waves' DMAs for tile j+2 to overwrite it
    asm volatile("s_waitcnt lgkmcnt(0)" ::: "memory");
    __builtin_amdgcn_s_barrier();
  }

  // ---- epilogue: normalize and write y (bf16, [b][t][h*128+d]) ----
  {
    float inv = 1.0f / l_i;
    int q = qw + l16;
    ushort* yrow = yb + ((size_t)(b * TT + q)) * DM + h * HD;
#pragma unroll
    for (int dmt = 0; dmt < 8; ++dmt) {
      us4 w = {f2b(o[dmt][0] * inv), f2b(o[dmt][1] * inv),
               f2b(o[dmt][2] * inv), f2b(o[dmt][3] * inv)};
      *(us4*)(yrow + dmt * 16 + quad * 4) = w;
    }
  }
}

// ---------------- launch ----------------
extern "C" void kernel_launch(void* const* d_in, const int* in_sizes, int n_in,
                              void* d_out, int out_size, void* d_ws, size_t ws_size,
                              hipStream_t stream) {
  const float* x = (const float*)d_in[0];
  // d_in[1] = attn_mask: ignored (exact causal mask computed analytically)
  const float* Wq = (const float*)d_in[2];
  const float* Wk = (const float*)d_in[3];
  const float* Wv = (const float*)d_in[4];
  const float* Wo = (const float*)d_in[5];
  const float* wlog = (const float*)d_in[6];
  // d_in[7] = weight_values: unused by the reference

  char* ws = (char*)d_ws;
  ushort* xb = (ushort*)ws;     ws += (size_t)4096 * 2048 * 2;
  ushort* Wqkvt = (ushort*)ws;  ws += (size_t)3072 * 2048 * 2;
  ushort* Wot = (ushort*)ws;    ws += (size_t)2048 * 2048 * 2;
  ushort* qbuf = (ushort*)ws;   ws += (size_t)4096 * 2048 * 2;
  ushort* kbuf = (ushort*)ws;   ws += (size_t)2 * KVH * 2048 * 128 * 2;
  ushort* vbuf = (ushort*)ws;   ws += (size_t)2 * KVH * 2048 * 128 * 2;
  ushort* ybuf = (ushort*)ws;   ws += (size_t)4096 * 2048 * 2;

  prep_kernel<<<dim3(96, 64, 3), dim3(32, 8), 0, stream>>>(
      x, Wq, Wk, Wv, Wo, xb, Wqkvt, Wot);
  gemm_qkv<<<dim3(12, 16), 512, 0, stream>>>(xb, Wqkvt, qbuf, kbuf, vbuf, 2048);
  attn_kernel<<<512, 512, 0, stream>>>(qbuf, kbuf, vbuf, ybuf, wlog);
  gemm_out<<<dim3(16, 16), 512, 0, stream>>>(ybuf, Wot, (float*)d_out, 2048, 2048);
}

// Round 13
// 296.333 us; speedup vs baseline: 1.0248x; 1.0148x over previous
//
#include <hip/hip_runtime.h>
#include <hip/hip_bf16.h>

#define TT 2048
#define DM 2048
#define NH 16
#define KVH 4
#define HD 128

typedef __attribute__((ext_vector_type(8))) short bs8;
typedef __attribute__((ext_vector_type(4))) float fx4;
typedef __attribute__((ext_vector_type(4))) unsigned short us4;
typedef __attribute__((ext_vector_type(8))) unsigned short us8;

#if __has_builtin(__builtin_amdgcn_exp2f)
#define EXP2(x) __builtin_amdgcn_exp2f(x)
#else
#define EXP2(x) exp2f(x)
#endif

__device__ inline unsigned short f2b(float f) {
  __hip_bfloat16 h = __float2bfloat16(f);
  return *reinterpret_cast<unsigned short*>(&h);
}

__device__ inline float b2f(unsigned short u) {
  unsigned int v = ((unsigned int)u) << 16;
  return *reinterpret_cast<float*>(&v);
}

__device__ inline void gld_lds16(const ushort* g, ushort* l) {
  __builtin_amdgcn_global_load_lds(
      (const __attribute__((address_space(1))) void*)g,
      (__attribute__((address_space(3))) void*)l,
      16, 0, 0);
}

// ---------------- prep: weight transposes + x cast, one dispatch ----------------
// z=0: Wqkvt[3072][2048] from Wq|Wk|Wv   z=1: Wot[2048][2048] from Wo
// z=2: x fp32 -> bf16 cast (linear)
__global__ __launch_bounds__(256) void prep_kernel(
    const float* __restrict__ x, const float* __restrict__ Wq,
    const float* __restrict__ Wk, const float* __restrict__ Wv,
    const float* __restrict__ Wo, ushort* __restrict__ xb,
    ushort* __restrict__ Wqkvt, ushort* __restrict__ Wot) {
  int tx = threadIdx.x, ty = threadIdx.y;  // block (32,8)
  if (blockIdx.z == 2) {
    int lin = (blockIdx.y * 96 + blockIdx.x) * 256 + ty * 32 + tx;
#pragma unroll
    for (int it = 0; it < 2; ++it) {
      int i = lin + it * (6144 * 256);
      if (i < (TT * 2 * DM) / 4) {
        float4 v = ((const float4*)x)[i];
        us4 o = {f2b(v.x), f2b(v.y), f2b(v.z), f2b(v.w)};
        ((us4*)xb)[i] = o;
      }
    }
    return;
  }
  __shared__ float t[32][33];
  int n0 = blockIdx.x * 32, k0 = blockIdx.y * 32;
  if (blockIdx.z == 0) {
    const float* src;
    int srcN, col0;
    if (n0 < 2048) { src = Wq; srcN = 2048; col0 = n0; }
    else if (n0 < 2560) { src = Wk; srcN = 512; col0 = n0 - 2048; }
    else { src = Wv; srcN = 512; col0 = n0 - 2560; }
    for (int jj = 0; jj < 4; ++jj)
      t[ty + jj * 8][tx] = src[(size_t)(k0 + ty + jj * 8) * srcN + col0 + tx];
    __syncthreads();
    for (int jj = 0; jj < 4; ++jj)
      Wqkvt[(size_t)(n0 + ty + jj * 8) * 2048 + k0 + tx] = f2b(t[tx][ty + jj * 8]);
  } else {
    if (n0 >= 2048) return;
    for (int jj = 0; jj < 4; ++jj)
      t[ty + jj * 8][tx] = Wo[(size_t)(k0 + ty + jj * 8) * 2048 + n0 + tx];
    __syncthreads();
    for (int jj = 0; jj < 4; ++jj)
      Wot[(size_t)(n0 + ty + jj * 8) * 2048 + k0 + tx] = f2b(t[tx][ty + jj * 8]);
  }
}

// ---------------- fused QKV GEMM: [4096 x 3072] = xb * Wqkvt^T ----------------
// 256x256 tile, BK=64, 8 waves, 128 KB LDS double-buffer.
// ROUND-13: 4-phase interleave (T3-style). Each K-step splits into 4 quadrant
// phases, each {stage 2 DMAs of one half-tile of kt+1 | (p0: vmcnt(2)+barrier)
// | 8 ds_read_b128 | setprio+16 MFMA | barrier}. Buffer lifetimes IDENTICAL to
// the proven r10 schedule (kt+1 -> freed buffer; kt confirmed at p0 before any
// ds_read) — only barrier density changes, so no new race surface. This is the
// per-phase ds||G||MFMA interleave the T-catalog shows is the MfmaUtil lever
// (m218 counted-vmcnt-in-phase +38%; m196 coarse-split-without-interleave hurts).
#define EPI_STRIDE 136  // shorts; row stride for 128-col epilogue passes
#define VT_STRIDE 264   // shorts; d-row stride for transposed V passes (528 B)
__global__ __launch_bounds__(512, 2) void gemm_qkv(const ushort* __restrict__ A,
                                                   const ushort* __restrict__ Bt,
                                                   ushort* __restrict__ qo,
                                                   ushort* __restrict__ ko,
                                                   ushort* __restrict__ vo,
                                                   int K) {
  __shared__ alignas(16) ushort smem[65536];  // 128 KB
  // As buf c: smem + c*16384 ; Bs buf c: smem + 32768 + c*16384
  const int tid = threadIdx.x;
  const int lane = tid & 63;
  const int wid = tid >> 6;        // 0..7
  const int wm = wid >> 2;         // 0..1  (output row half)
  const int wn = wid & 3;          // 0..3  (output col quarter)
  const int quad = lane >> 4, l16 = lane & 15;
  const int swl = l16 & 7;
  const int bm = blockIdx.y * 256, bn = blockIdx.x * 256;
  const int r8 = lane >> 3, s8 = lane & 7;
  const int cst = s8 ^ r8;         // staging chunk swizzle (m&7 == r8)

  fx4 acc[8][4];
#pragma unroll
  for (int i = 0; i < 8; ++i)
#pragma unroll
    for (int j = 0; j < 4; ++j) acc[i][j] = (fx4){0.f, 0.f, 0.f, 0.f};

  // per-thread staging base pointers (stripe s adds s*64 rows)
  const ushort* apA = A + (size_t)(bm + wid * 8 + r8) * K + cst * 8;
  const ushort* apB = Bt + (size_t)(bn + wid * 8 + r8) * K + cst * 8;
  const int dofs = (wid * 8) * 64;  // LDS dest offset within buffer (lane adds 16B)

  // ---- prologue: stage tile 0 into buf 0 (counted wait in-loop) ----
#pragma unroll
  for (int s = 0; s < 4; ++s) {
    gld_lds16(apA + (size_t)(s * 64) * K, smem + dofs + s * 4096);
    gld_lds16(apB + (size_t)(s * 64) * K, smem + 32768 + dofs + s * 4096);
  }

  const int NT = K >> 6;
  for (int kt = 0; kt < NT; ++kt) {
    const int cur = kt & 1, nxt = cur ^ 1;
    const ushort* As = smem + cur * 16384;
    const ushort* Bs = smem + 32768 + cur * 16384;
    const bool pf = (kt + 1 < NT);
    const ushort* sa = apA + (kt + 1) * 64;
    const ushort* sb = apB + (kt + 1) * 64;
    ushort* dA = smem + nxt * 16384 + dofs;
    ushort* dB = smem + 32768 + nxt * 16384 + dofs;

#pragma unroll
    for (int p = 0; p < 4; ++p) {
      // ---- stage one half-tile of kt+1 (2 DMAs) into the freed buffer ----
      if (pf) {
        if (p == 0) {
          gld_lds16(sa, dA);
          gld_lds16(sa + (size_t)64 * K, dA + 4096);
        } else if (p == 1) {
          gld_lds16(sa + (size_t)128 * K, dA + 8192);
          gld_lds16(sa + (size_t)192 * K, dA + 12288);
        } else if (p == 2) {
          gld_lds16(sb, dB);
          gld_lds16(sb + (size_t)64 * K, dB + 4096);
        } else {
          gld_lds16(sb + (size_t)128 * K, dB + 8192);
          gld_lds16(sb + (size_t)192 * K, dB + 12288);
        }
      }
      if (p == 0) {
        // tile kt's 8 loads (oldest outstanding) landed; kt+1's stay in flight
        if (pf) asm volatile("s_waitcnt vmcnt(2)" ::: "memory");
        else    asm volatile("s_waitcnt vmcnt(0)" ::: "memory");
        __builtin_amdgcn_s_barrier();
      }
      const int ks = p >> 1, mh = p & 1;
      const int so = (((ks * 4 + quad) ^ swl) << 3);  // swizzled 16B slot
      bs8 bf[4], af[4];
#pragma unroll
      for (int nt = 0; nt < 4; ++nt) {
        int n = wn * 64 + nt * 16 + l16;
        bf[nt] = *(const bs8*)(Bs + n * 64 + so);
      }
#pragma unroll
      for (int i = 0; i < 4; ++i) {
        int m = wm * 128 + (mh * 4 + i) * 16 + l16;
        af[i] = *(const bs8*)(As + m * 64 + so);
      }
      __builtin_amdgcn_s_setprio(1);
#pragma unroll
      for (int i = 0; i < 4; ++i)
#pragma unroll
        for (int nt = 0; nt < 4; ++nt)
          acc[mh * 4 + i][nt] = __builtin_amdgcn_mfma_f32_16x16x32_bf16(
              af[i], bf[nt], acc[mh * 4 + i][nt], 0, 0, 0);
      __builtin_amdgcn_s_setprio(0);
      if (p == 3)  // my reads of buf cur complete before licensing overwrite
        asm volatile("s_waitcnt lgkmcnt(0)" ::: "memory");
      __builtin_amdgcn_s_barrier();  // phase lock / tile-end licensing
    }
  }

  // ---- epilogue: two 128-column passes through LDS ----
  if (bn < 2560) {
    // q / k: row-major [256][136] per pass
#pragma unroll
    for (int h = 0; h < 2; ++h) {
      if ((wn >> 1) == h) {
#pragma unroll
        for (int mt = 0; mt < 8; ++mt)
#pragma unroll
          for (int nt = 0; nt < 4; ++nt)
#pragma unroll
            for (int r = 0; r < 4; ++r) {
              int row = wm * 128 + mt * 16 + quad * 4 + r;      // 0..255
              int col = (wn & 1) * 64 + nt * 16 + l16;          // 0..127
              smem[row * EPI_STRIDE + col] = f2b(acc[mt][nt][r]);
            }
      }
      __builtin_amdgcn_s_barrier();
      const int rsel = tid >> 4;   // 0..31
      const int csel = tid & 15;   // 16B chunk
      for (int ii = 0; ii < 8; ++ii) {
        int row = ii * 32 + rsel;
        us8 chunk = *(const us8*)(smem + row * EPI_STRIDE + csel * 8);
        int row_g = bm + row;
        int colc = bn + h * 128 + csel * 8;
        if (bn < 2048) {
          *(us8*)(qo + (size_t)row_g * 2048 + colc) = chunk;
        } else {
          int b = row_g >> 11, t = row_g & 2047;
          int kc = colc - 2048;
          int gg = kc >> 7, d = kc & 127;
          *(us8*)(ko + ((size_t)(b * KVH + gg) * TT + t) * HD + d) = chunk;
        }
      }
      __builtin_amdgcn_s_barrier();
    }
  } else {
    // V: transposed [d_local 0..127][token 0..255] per pass, stride 264
    const int b = bm >> 11;        // 256-row tile never straddles b (2048%256==0)
    const int t0 = bm & 2047;
#pragma unroll
    for (int h = 0; h < 2; ++h) {
      if ((wn >> 1) == h) {
#pragma unroll
        for (int mt = 0; mt < 8; ++mt)
#pragma unroll
          for (int nt = 0; nt < 4; ++nt)
#pragma unroll
            for (int r = 0; r < 4; ++r) {
              int row = wm * 128 + mt * 16 + quad * 4 + r;      // token_local
              int col = (wn & 1) * 64 + nt * 16 + l16;          // d_local
              smem[col * VT_STRIDE + row] = f2b(acc[mt][nt][r]);
            }
      }
      __builtin_amdgcn_s_barrier();
      const int tc = tid & 31;     // token chunk (8 tokens)
      const int dr = tid >> 5;     // 0..15
      for (int it = 0; it < 8; ++it) {
        int d_local = it * 16 + dr;                        // 0..127
        us8 chunk = *(const us8*)(smem + d_local * VT_STRIDE + tc * 8);
        int vc = (bn - 2560) + h * 128 + d_local;          // 0..511
        int gg = vc >> 7, dd = vc & 127;
        *(us8*)(vo + ((size_t)(b * KVH + gg) * HD + dd) * TT + t0 + tc * 8) = chunk;
      }
      __builtin_amdgcn_s_barrier();
    }
  }
}

// ---------------- output-projection GEMM: fp32 out ----------------
// r12-proven: 256x128 tile, 256 blocks = 100% fill, counted-vmcnt schedule.
__global__ __launch_bounds__(512, 2) void gemm_out(const ushort* __restrict__ A,
                                                   const ushort* __restrict__ Bt,
                                                   float* __restrict__ Cout,
                                                   int N, int K) {
  __shared__ alignas(16) ushort smem[49152];  // 96 KB
  // A buf c: smem + c*16384 (256x64) ; B buf c: smem + 32768 + c*8192 (128x64)
  const int tid = threadIdx.x;
  const int lane = tid & 63;
  const int wid = tid >> 6;        // 0..7
  const int wm = wid >> 1;         // 0..3 (64-row band of 256)
  const int wn = wid & 1;          // 0..1 (64-col half of 128)
  const int quad = lane >> 4, l16 = lane & 15;
  const int swl = l16 & 7;
  const int bm = blockIdx.y * 256, bn = blockIdx.x * 128;
  const int r8 = lane >> 3, s8 = lane & 7;
  const int cst = s8 ^ r8;         // staging chunk swizzle (m&7 == r8)

  fx4 acc[4][4];
#pragma unroll
  for (int i = 0; i < 4; ++i)
#pragma unroll
    for (int j = 0; j < 4; ++j) acc[i][j] = (fx4){0.f, 0.f, 0.f, 0.f};

  const ushort* apA = A + (size_t)(bm + wid * 8 + r8) * K + cst * 8;
  const ushort* apB = Bt + (size_t)(bn + wid * 8 + r8) * K + cst * 8;
  const int dofs = (wid * 8) * 64;

  // ---- prologue: stage tile 0 into buf 0 (counted wait in-loop) ----
#pragma unroll
  for (int s = 0; s < 4; ++s)
    gld_lds16(apA + (size_t)(s * 64) * K, smem + dofs + s * 4096);
#pragma unroll
  for (int s = 0; s < 2; ++s)
    gld_lds16(apB + (size_t)(s * 64) * K, smem + 32768 + dofs + s * 4096);

  const int NT = K >> 6;
  for (int kt = 0; kt < NT; ++kt) {
    const int cur = kt & 1, nxt = cur ^ 1;
    const ushort* As = smem + cur * 16384;
    const ushort* Bs = smem + 32768 + cur * 8192;
    if (kt + 1 < NT) {
      const ushort* sa = apA + (kt + 1) * 64;
      const ushort* sb = apB + (kt + 1) * 64;
      ushort* dA = smem + nxt * 16384 + dofs;
      ushort* dB = smem + 32768 + nxt * 8192 + dofs;
#pragma unroll
      for (int s = 0; s < 4; ++s)
        gld_lds16(sa + (size_t)(s * 64) * K, dA + s * 4096);
#pragma unroll
      for (int s = 0; s < 2; ++s)
        gld_lds16(sb + (size_t)(s * 64) * K, dB + s * 4096);
      asm volatile("s_waitcnt vmcnt(6)" ::: "memory");  // kt landed, kt+1 in flight
    } else {
      asm volatile("s_waitcnt vmcnt(0)" ::: "memory");
    }
    __builtin_amdgcn_s_barrier();

#pragma unroll
    for (int ks = 0; ks < 2; ++ks) {
      const int so = (((ks * 4 + quad) ^ swl) << 3);
      bs8 af[4], bf[4];
#pragma unroll
      for (int mt = 0; mt < 4; ++mt) {
        int m = wm * 64 + mt * 16 + l16;
        af[mt] = *(const bs8*)(As + m * 64 + so);
      }
#pragma unroll
      for (int nt = 0; nt < 4; ++nt) {
        int n = wn * 64 + nt * 16 + l16;
        bf[nt] = *(const bs8*)(Bs + n * 64 + so);
      }
      __builtin_amdgcn_s_setprio(1);
#pragma unroll
      for (int mt = 0; mt < 4; ++mt)
#pragma unroll
        for (int nt = 0; nt < 4; ++nt)
          acc[mt][nt] = __builtin_amdgcn_mfma_f32_16x16x32_bf16(af[mt], bf[nt],
                                                                acc[mt][nt], 0, 0, 0);
      __builtin_amdgcn_s_setprio(0);
    }
    asm volatile("s_waitcnt lgkmcnt(0)" ::: "memory");
    __builtin_amdgcn_s_barrier();
  }

  // ---- epilogue: bf16 LDS round-trip [256][136] (overlays buffers) ----
  for (int mt = 0; mt < 4; ++mt)
    for (int nt = 0; nt < 4; ++nt)
      for (int r = 0; r < 4; ++r) {
        int row = wm * 64 + mt * 16 + quad * 4 + r;   // 0..255
        int col = wn * 64 + nt * 16 + l16;            // 0..127
        smem[row * EPI_STRIDE + col] = f2b(acc[mt][nt][r]);
      }
  __syncthreads();
  const int rsel = tid >> 4;   // 0..31
  const int csel = tid & 15;   // 16B chunk
  for (int ii = 0; ii < 8; ++ii) {
    int row = ii * 32 + rsel;
    us8 chunk = *(const us8*)(smem + row * EPI_STRIDE + csel * 8);
    int row_g = bm + row;
    int colc = bn + csel * 8;
    float4 lo = {b2f(chunk[0]), b2f(chunk[1]), b2f(chunk[2]), b2f(chunk[3])};
    float4 hi = {b2f(chunk[4]), b2f(chunk[5]), b2f(chunk[6]), b2f(chunk[7])};
    *(float4*)(Cout + (size_t)row_g * N + colc) = lo;
    *(float4*)(Cout + (size_t)row_g * N + colc + 4) = hi;
  }
}

// ---------------- fused causal WGQA attention, 8-wave blocks ----------------
// Verbatim proven 70.5 us version. Ledger: 32q/wave (r2) concurrency-bound;
// V-from-L2 (r3) latency-bound; split-key partials (r5) VGPR spill. Local opt.
__global__ __launch_bounds__(512, 4) void attn_kernel(const ushort* __restrict__ qb,
                                                      const ushort* __restrict__ kb,
                                                      const ushort* __restrict__ vt,
                                                      ushort* __restrict__ yb,
                                                      const float* __restrict__ wlog) {
  __shared__ alignas(16) ushort Ks[2][64 * 128];   // [buf][key][d], chunk-swizzled
  __shared__ alignas(16) ushort Vs[2][128 * 64];   // [buf][d][key], chunk-swizzled
  __shared__ alignas(16) ushort Ps[128 * 64];      // [q][key], chunk-XOR swizzled

  const int bid = blockIdx.x;
  const int qt = (bid & 256) ? (bid & 15) : 15 - (bid & 15);
  const int h = (bid >> 4) & 15;
  const int b = bid >> 8;
  const int g = h >> 2;
  const int tid = threadIdx.x;
  const int lane = tid & 63;
  const int wid = tid >> 6;        // 0..7
  const int quad = lane >> 4;
  const int l16 = lane & 15;
  const int qw = qt * 128 + wid * 16;   // wave's first query

  const float scale = wlog[g] * 0.08838834764831845f;  // 1/sqrt(128)
  const float sc2 = scale * 1.4426950408889634f;       // * log2(e)

  const ushort* kbase = kb + (size_t)(b * KVH + g) * TT * HD;
  const ushort* vbase = vt + (size_t)(b * KVH + g) * HD * TT;

  // persistent staging pointers; each thread stages 2 K-slots + 2 V-slots
  const ushort* kp;
  const ushort* vp;
  {
    int keyr = wid * 4 + (lane >> 4);          // 0..31
    int si = lane & 15;
    int ck = (si & 8) | ((si ^ keyr) & 7);
    kp = kbase + (size_t)keyr * HD + ck * 8;
    int dr = wid * 8 + (lane >> 3);            // 0..63
    int s8 = lane & 7;
    int cv = s8 ^ (dr & 7);
    vp = vbase + (size_t)dr * TT + cv * 8;
  }

  // ---- prologue: stage tile 0 into buffer 0 (DMA runs under Q-load) ----
  gld_lds16(kp, &Ks[0][wid * 512]);
  gld_lds16(kp + 32 * HD, &Ks[0][4096 + wid * 512]);
  gld_lds16(vp, &Vs[0][wid * 512]);
  gld_lds16(vp + 64 * TT, &Vs[0][4096 + wid * 512]);
  kp += 64 * HD;
  vp += 64;

  // Q fragments in registers (B-operand of S^T = K * Q^T)
  bs8 qf[4];
  {
    int q = qw + l16;
    const ushort* qrow = qb + ((size_t)(b * TT + q)) * DM + h * HD;
#pragma unroll
    for (int ks = 0; ks < 4; ++ks)
      qf[ks] = *(const bs8*)(qrow + ks * 32 + quad * 8);
  }

  float m_i = -INFINITY;  // running max of RAW logits
  float l_i = 0.f;
  fx4 o[8];
#pragma unroll
  for (int i = 0; i < 8; ++i) o[i] = (fx4){0.f, 0.f, 0.f, 0.f};

  const int jmax = 2 * qt + 1;
  for (int j = 0; j <= jmax; ++j) {
    const int cur = j & 1;
    // ---- issue NEXT tile's DMAs first, then wait only for tile j ----
    if (j < jmax) {
      const int nxt = cur ^ 1;
      gld_lds16(kp, &Ks[nxt][wid * 512]);
      gld_lds16(kp + 32 * HD, &Ks[nxt][4096 + wid * 512]);
      gld_lds16(vp, &Vs[nxt][wid * 512]);
      gld_lds16(vp + 64 * TT, &Vs[nxt][4096 + wid * 512]);
      kp += 64 * HD;
      vp += 64;
      asm volatile("s_waitcnt vmcnt(4)" ::: "memory");  // tile j done, j+1 in flight
    } else {
      asm volatile("s_waitcnt vmcnt(0)" ::: "memory");
    }
    __builtin_amdgcn_s_barrier();

    if (j * 64 <= qw + 15) {  // wave has at least one unmasked key
      const ushort* Kc = Ks[cur];
      const ushort* Vc = Vs[cur];
      // ---- S^T = K * Q^T  (64 keys x 16 queries), fp32 acc ----
      fx4 s[4];
#pragma unroll
      for (int mt = 0; mt < 4; ++mt) s[mt] = (fx4){0.f, 0.f, 0.f, 0.f};
      __builtin_amdgcn_s_setprio(1);
#pragma unroll
      for (int mt = 0; mt < 4; ++mt) {
        bs8 a[4];
        int key = mt * 16 + l16;
#pragma unroll
        for (int ks = 0; ks < 4; ++ks) {
          int c = ks * 4 + quad;
          int slot = (c & 8) | ((c ^ key) & 7);
          a[ks] = *(const bs8*)(Kc + key * 128 + slot * 8);
        }
#pragma unroll
        for (int ks = 0; ks < 4; ++ks)
          s[mt] = __builtin_amdgcn_mfma_f32_16x16x32_bf16(a[ks], qf[ks],
                                                          s[mt], 0, 0, 0);
      }
      __builtin_amdgcn_s_setprio(0);

      // ---- causal mask: needed iff tile max key > wave min query ----
      const int q = qw + l16;
      if (j * 64 + 63 > qw) {
#pragma unroll
        for (int mt = 0; mt < 4; ++mt)
#pragma unroll
          for (int r = 0; r < 4; ++r) {
            int key = j * 64 + mt * 16 + quad * 4 + r;
            if (key > q) s[mt][r] = -1e30f;
          }
      }
      float mx = s[0][0];
#pragma unroll
      for (int mt = 0; mt < 4; ++mt)
#pragma unroll
        for (int r = 0; r < 4; ++r) mx = fmaxf(mx, s[mt][r]);
      mx = fmaxf(mx, __shfl_xor(mx, 16));
      mx = fmaxf(mx, __shfl_xor(mx, 32));

      // ---- defer-max: only rescale when the max actually grows (>8 scaled) ----
      if (!__all((mx - m_i) * scale <= 8.0f)) {
        float m_new = fmaxf(m_i, mx);
        float alpha = EXP2((m_i - m_new) * sc2);
        l_i *= alpha;
#pragma unroll
        for (int dmt = 0; dmt < 8; ++dmt)
#pragma unroll
          for (int r = 0; r < 4; ++r) o[dmt][r] *= alpha;
        m_i = m_new;
      }
      float negb = -m_i * sc2;
      float sum = 0.f;
#pragma unroll
      for (int mt = 0; mt < 4; ++mt)
#pragma unroll
        for (int r = 0; r < 4; ++r) {
          float pv = EXP2(fmaf(s[mt][r], sc2, negb));
          s[mt][r] = pv;
          sum += pv;
        }
      sum += __shfl_xor(sum, 16);
      sum += __shfl_xor(sum, 32);
      l_i += sum;

      // P (bf16) to LDS, [q][key] stride 64 with chunk-XOR swizzle;
      // wave touches only its own 16 rows -> no barrier needed
      int qrow = wid * 16 + l16;
      int sw = l16 & 7;
#pragma unroll
      for (int mt = 0; mt < 4; ++mt) {
        us4 pw = {f2b(s[mt][0]), f2b(s[mt][1]), f2b(s[mt][2]), f2b(s[mt][3])};
        int chunk = mt * 2 + (quad >> 1);
        *(us4*)(Ps + qrow * 64 + ((chunk ^ sw) << 3) + ((quad & 1) << 2)) = pw;
      }

      // ---- O^T += V^T * P^T  (no barrier: wave reads only its own P rows) ----
#pragma unroll
      for (int ks = 0; ks < 2; ++ks) {
        bs8 pb = *(const bs8*)(Ps + qrow * 64 + (((ks * 4 + quad) ^ sw) << 3));
        __builtin_amdgcn_s_setprio(1);
#pragma unroll
        for (int dmt = 0; dmt < 8; ++dmt) {
          int d = dmt * 16 + l16;
          int c = ks * 4 + quad;
          int slot = c ^ (d & 7);
          bs8 va = *(const bs8*)(Vc + d * 64 + slot * 8);
          o[dmt] = __builtin_amdgcn_mfma_f32_16x16x32_bf16(va, pb, o[dmt], 0, 0, 0);
        }
        __builtin_amdgcn_s_setprio(0);
      }
    }
    // all my LDS reads of buf[cur] must be complete before signaling; the
    // barrier then licenses other waves' DMAs for tile j+2 to overwrite it
    asm volatile("s_waitcnt lgkmcnt(0)" ::: "memory");
    __builtin_amdgcn_s_barrier();
  }

  // ---- epilogue: normalize and write y (bf16, [b][t][h*128+d]) ----
  {
    float inv = 1.0f / l_i;
    int q = qw + l16;
    ushort* yrow = yb + ((size_t)(b * TT + q)) * DM + h * HD;
#pragma unroll
    for (int dmt = 0; dmt < 8; ++dmt) {
      us4 w = {f2b(o[dmt][0] * inv), f2b(o[dmt][1] * inv),
               f2b(o[dmt][2] * inv), f2b(o[dmt][3] * inv)};
      *(us4*)(yrow + dmt * 16 + quad * 4) = w;
    }
  }
}

// ---------------- launch ----------------
extern "C" void kernel_launch(void* const* d_in, const int* in_sizes, int n_in,
                              void* d_out, int out_size, void* d_ws, size_t ws_size,
                              hipStream_t stream) {
  const float* x = (const float*)d_in[0];
  // d_in[1] = attn_mask: ignored (exact causal mask computed analytically)
  const float* Wq = (const float*)d_in[2];
  const float* Wk = (const float*)d_in[3];
  const float* Wv = (const float*)d_in[4];
  const float* Wo = (const float*)d_in[5];
  const float* wlog = (const float*)d_in[6];
  // d_in[7] = weight_values: unused by the reference

  char* ws = (char*)d_ws;
  ushort* xb = (ushort*)ws;     ws += (size_t)4096 * 2048 * 2;
  ushort* Wqkvt = (ushort*)ws;  ws += (size_t)3072 * 2048 * 2;
  ushort* Wot = (ushort*)ws;    ws += (size_t)2048 * 2048 * 2;
  ushort* qbuf = (ushort*)ws;   ws += (size_t)4096 * 2048 * 2;
  ushort* kbuf = (ushort*)ws;   ws += (size_t)2 * KVH * 2048 * 128 * 2;
  ushort* vbuf = (ushort*)ws;   ws += (size_t)2 * KVH * 2048 * 128 * 2;
  ushort* ybuf = (ushort*)ws;   ws += (size_t)4096 * 2048 * 2;

  prep_kernel<<<dim3(96, 64, 3), dim3(32, 8), 0, stream>>>(
      x, Wq, Wk, Wv, Wo, xb, Wqkvt, Wot);
  gemm_qkv<<<dim3(12, 16), 512, 0, stream>>>(xb, Wqkvt, qbuf, kbuf, vbuf, 2048);
  attn_kernel<<<512, 512, 0, stream>>>(qbuf, kbuf, vbuf, ybuf, wlog);
  gemm_out<<<dim3(16, 16), 512, 0, stream>>>(ybuf, Wot, (float*)d_out, 2048, 2048);
}

// Round 14
// 294.041 us; speedup vs baseline: 1.0328x; 1.0078x over previous
//
#include <hip/hip_runtime.h>
#include <hip/hip_bf16.h>

#define TT 2048
#define DM 2048
#define NH 16
#define KVH 4
#define HD 128

typedef __attribute__((ext_vector_type(8))) short bs8;
typedef __attribute__((ext_vector_type(4))) float fx4;
typedef __attribute__((ext_vector_type(4))) unsigned short us4;
typedef __attribute__((ext_vector_type(8))) unsigned short us8;

#if __has_builtin(__builtin_amdgcn_exp2f)
#define EXP2(x) __builtin_amdgcn_exp2f(x)
#else
#define EXP2(x) exp2f(x)
#endif

__device__ inline unsigned short f2b(float f) {
  __hip_bfloat16 h = __float2bfloat16(f);
  return *reinterpret_cast<unsigned short*>(&h);
}

__device__ inline float b2f(unsigned short u) {
  unsigned int v = ((unsigned int)u) << 16;
  return *reinterpret_cast<float*>(&v);
}

__device__ inline void gld_lds16(const ushort* g, ushort* l) {
  __builtin_amdgcn_global_load_lds(
      (const __attribute__((address_space(1))) void*)g,
      (__attribute__((address_space(3))) void*)l,
      16, 0, 0);
}

// ---------------- prep: weight transposes + x cast, one dispatch ----------------
// z=0: Wqkvt[3072][2048] from Wq|Wk|Wv   z=1: Wot[2048][2048] from Wo
// z=2: x fp32 -> bf16 cast (linear)
__global__ __launch_bounds__(256) void prep_kernel(
    const float* __restrict__ x, const float* __restrict__ Wq,
    const float* __restrict__ Wk, const float* __restrict__ Wv,
    const float* __restrict__ Wo, ushort* __restrict__ xb,
    ushort* __restrict__ Wqkvt, ushort* __restrict__ Wot) {
  int tx = threadIdx.x, ty = threadIdx.y;  // block (32,8)
  if (blockIdx.z == 2) {
    int lin = (blockIdx.y * 96 + blockIdx.x) * 256 + ty * 32 + tx;
#pragma unroll
    for (int it = 0; it < 2; ++it) {
      int i = lin + it * (6144 * 256);
      if (i < (TT * 2 * DM) / 4) {
        float4 v = ((const float4*)x)[i];
        us4 o = {f2b(v.x), f2b(v.y), f2b(v.z), f2b(v.w)};
        ((us4*)xb)[i] = o;
      }
    }
    return;
  }
  __shared__ float t[32][33];
  int n0 = blockIdx.x * 32, k0 = blockIdx.y * 32;
  if (blockIdx.z == 0) {
    const float* src;
    int srcN, col0;
    if (n0 < 2048) { src = Wq; srcN = 2048; col0 = n0; }
    else if (n0 < 2560) { src = Wk; srcN = 512; col0 = n0 - 2048; }
    else { src = Wv; srcN = 512; col0 = n0 - 2560; }
    for (int jj = 0; jj < 4; ++jj)
      t[ty + jj * 8][tx] = src[(size_t)(k0 + ty + jj * 8) * srcN + col0 + tx];
    __syncthreads();
    for (int jj = 0; jj < 4; ++jj)
      Wqkvt[(size_t)(n0 + ty + jj * 8) * 2048 + k0 + tx] = f2b(t[tx][ty + jj * 8]);
  } else {
    if (n0 >= 2048) return;
    for (int jj = 0; jj < 4; ++jj)
      t[ty + jj * 8][tx] = Wo[(size_t)(k0 + ty + jj * 8) * 2048 + n0 + tx];
    __syncthreads();
    for (int jj = 0; jj < 4; ++jj)
      Wot[(size_t)(n0 + ty + jj * 8) * 2048 + k0 + tx] = f2b(t[tx][ty + jj * 8]);
  }
}

// ---------------- fused QKV GEMM: [4096 x 3072] = xb * Wqkvt^T ----------------
// 256x256 tile, BK=64, 8 waves, 128 KB LDS double-buffer.
// r13-proven: 4-phase interleave. Each K-step = 4 quadrant phases, each
// {stage 2 DMAs of kt+1 | (p0: vmcnt(2)+barrier) | 8 ds_read | 16 MFMA |
// barrier}. Buffer lifetimes identical to the r10 schedule. (-4 us vs r12.)
#define EPI_STRIDE 136  // shorts; row stride for 128-col epilogue passes
#define VT_STRIDE 264   // shorts; d-row stride for transposed V passes (528 B)
__global__ __launch_bounds__(512, 2) void gemm_qkv(const ushort* __restrict__ A,
                                                   const ushort* __restrict__ Bt,
                                                   ushort* __restrict__ qo,
                                                   ushort* __restrict__ ko,
                                                   ushort* __restrict__ vo,
                                                   int K) {
  __shared__ alignas(16) ushort smem[65536];  // 128 KB
  // As buf c: smem + c*16384 ; Bs buf c: smem + 32768 + c*16384
  const int tid = threadIdx.x;
  const int lane = tid & 63;
  const int wid = tid >> 6;        // 0..7
  const int wm = wid >> 2;         // 0..1  (output row half)
  const int wn = wid & 3;          // 0..3  (output col quarter)
  const int quad = lane >> 4, l16 = lane & 15;
  const int swl = l16 & 7;
  const int bm = blockIdx.y * 256, bn = blockIdx.x * 256;
  const int r8 = lane >> 3, s8 = lane & 7;
  const int cst = s8 ^ r8;         // staging chunk swizzle (m&7 == r8)

  fx4 acc[8][4];
#pragma unroll
  for (int i = 0; i < 8; ++i)
#pragma unroll
    for (int j = 0; j < 4; ++j) acc[i][j] = (fx4){0.f, 0.f, 0.f, 0.f};

  // per-thread staging base pointers (stripe s adds s*64 rows)
  const ushort* apA = A + (size_t)(bm + wid * 8 + r8) * K + cst * 8;
  const ushort* apB = Bt + (size_t)(bn + wid * 8 + r8) * K + cst * 8;
  const int dofs = (wid * 8) * 64;  // LDS dest offset within buffer (lane adds 16B)

  // ---- prologue: stage tile 0 into buf 0 (counted wait in-loop) ----
#pragma unroll
  for (int s = 0; s < 4; ++s) {
    gld_lds16(apA + (size_t)(s * 64) * K, smem + dofs + s * 4096);
    gld_lds16(apB + (size_t)(s * 64) * K, smem + 32768 + dofs + s * 4096);
  }

  const int NT = K >> 6;
  for (int kt = 0; kt < NT; ++kt) {
    const int cur = kt & 1, nxt = cur ^ 1;
    const ushort* As = smem + cur * 16384;
    const ushort* Bs = smem + 32768 + cur * 16384;
    const bool pf = (kt + 1 < NT);
    const ushort* sa = apA + (kt + 1) * 64;
    const ushort* sb = apB + (kt + 1) * 64;
    ushort* dA = smem + nxt * 16384 + dofs;
    ushort* dB = smem + 32768 + nxt * 16384 + dofs;

#pragma unroll
    for (int p = 0; p < 4; ++p) {
      // ---- stage one half-tile of kt+1 (2 DMAs) into the freed buffer ----
      if (pf) {
        if (p == 0) {
          gld_lds16(sa, dA);
          gld_lds16(sa + (size_t)64 * K, dA + 4096);
        } else if (p == 1) {
          gld_lds16(sa + (size_t)128 * K, dA + 8192);
          gld_lds16(sa + (size_t)192 * K, dA + 12288);
        } else if (p == 2) {
          gld_lds16(sb, dB);
          gld_lds16(sb + (size_t)64 * K, dB + 4096);
        } else {
          gld_lds16(sb + (size_t)128 * K, dB + 8192);
          gld_lds16(sb + (size_t)192 * K, dB + 12288);
        }
      }
      if (p == 0) {
        // tile kt's 8 loads (oldest outstanding) landed; kt+1's stay in flight
        if (pf) asm volatile("s_waitcnt vmcnt(2)" ::: "memory");
        else    asm volatile("s_waitcnt vmcnt(0)" ::: "memory");
        __builtin_amdgcn_s_barrier();
      }
      const int ks = p >> 1, mh = p & 1;
      const int so = (((ks * 4 + quad) ^ swl) << 3);  // swizzled 16B slot
      bs8 bf[4], af[4];
#pragma unroll
      for (int nt = 0; nt < 4; ++nt) {
        int n = wn * 64 + nt * 16 + l16;
        bf[nt] = *(const bs8*)(Bs + n * 64 + so);
      }
#pragma unroll
      for (int i = 0; i < 4; ++i) {
        int m = wm * 128 + (mh * 4 + i) * 16 + l16;
        af[i] = *(const bs8*)(As + m * 64 + so);
      }
      __builtin_amdgcn_s_setprio(1);
#pragma unroll
      for (int i = 0; i < 4; ++i)
#pragma unroll
        for (int nt = 0; nt < 4; ++nt)
          acc[mh * 4 + i][nt] = __builtin_amdgcn_mfma_f32_16x16x32_bf16(
              af[i], bf[nt], acc[mh * 4 + i][nt], 0, 0, 0);
      __builtin_amdgcn_s_setprio(0);
      if (p == 3)  // my reads of buf cur complete before licensing overwrite
        asm volatile("s_waitcnt lgkmcnt(0)" ::: "memory");
      __builtin_amdgcn_s_barrier();  // phase lock / tile-end licensing
    }
  }

  // ---- epilogue: two 128-column passes through LDS ----
  if (bn < 2560) {
    // q / k: row-major [256][136] per pass
#pragma unroll
    for (int h = 0; h < 2; ++h) {
      if ((wn >> 1) == h) {
#pragma unroll
        for (int mt = 0; mt < 8; ++mt)
#pragma unroll
          for (int nt = 0; nt < 4; ++nt)
#pragma unroll
            for (int r = 0; r < 4; ++r) {
              int row = wm * 128 + mt * 16 + quad * 4 + r;      // 0..255
              int col = (wn & 1) * 64 + nt * 16 + l16;          // 0..127
              smem[row * EPI_STRIDE + col] = f2b(acc[mt][nt][r]);
            }
      }
      __builtin_amdgcn_s_barrier();
      const int rsel = tid >> 4;   // 0..31
      const int csel = tid & 15;   // 16B chunk
      for (int ii = 0; ii < 8; ++ii) {
        int row = ii * 32 + rsel;
        us8 chunk = *(const us8*)(smem + row * EPI_STRIDE + csel * 8);
        int row_g = bm + row;
        int colc = bn + h * 128 + csel * 8;
        if (bn < 2048) {
          *(us8*)(qo + (size_t)row_g * 2048 + colc) = chunk;
        } else {
          int b = row_g >> 11, t = row_g & 2047;
          int kc = colc - 2048;
          int gg = kc >> 7, d = kc & 127;
          *(us8*)(ko + ((size_t)(b * KVH + gg) * TT + t) * HD + d) = chunk;
        }
      }
      __builtin_amdgcn_s_barrier();
    }
  } else {
    // V: transposed [d_local 0..127][token 0..255] per pass, stride 264
    const int b = bm >> 11;        // 256-row tile never straddles b (2048%256==0)
    const int t0 = bm & 2047;
#pragma unroll
    for (int h = 0; h < 2; ++h) {
      if ((wn >> 1) == h) {
#pragma unroll
        for (int mt = 0; mt < 8; ++mt)
#pragma unroll
          for (int nt = 0; nt < 4; ++nt)
#pragma unroll
            for (int r = 0; r < 4; ++r) {
              int row = wm * 128 + mt * 16 + quad * 4 + r;      // token_local
              int col = (wn & 1) * 64 + nt * 16 + l16;          // d_local
              smem[col * VT_STRIDE + row] = f2b(acc[mt][nt][r]);
            }
      }
      __builtin_amdgcn_s_barrier();
      const int tc = tid & 31;     // token chunk (8 tokens)
      const int dr = tid >> 5;     // 0..15
      for (int it = 0; it < 8; ++it) {
        int d_local = it * 16 + dr;                        // 0..127
        us8 chunk = *(const us8*)(smem + d_local * VT_STRIDE + tc * 8);
        int vc = (bn - 2560) + h * 128 + d_local;          // 0..511
        int gg = vc >> 7, dd = vc & 127;
        *(us8*)(vo + ((size_t)(b * KVH + gg) * HD + dd) * TT + t0 + tc * 8) = chunk;
      }
      __builtin_amdgcn_s_barrier();
    }
  }
}

// ---------------- output-projection GEMM: fp32 out ----------------
// ROUND-14: 2-phase ks-split of the r12 counted-vmcnt K-loop (the
// no-duplication split for a 64x64 wave tile). Each phase = {issue 3 of
// kt+1's 6 DMAs | (p0: vmcnt(3)+barrier) | 8 ds_read | 16 MFMA |
// (p1: lgkmcnt(0)) | barrier}. At p0: outstanding = kt's 6 + kt+1's 3 = 9,
// vmcnt(3) drains exactly kt. 100% fill (256 blocks) so interleave gains
// are undiluted. Buffer lifetimes identical to r12.
__global__ __launch_bounds__(512, 2) void gemm_out(const ushort* __restrict__ A,
                                                   const ushort* __restrict__ Bt,
                                                   float* __restrict__ Cout,
                                                   int N, int K) {
  __shared__ alignas(16) ushort smem[49152];  // 96 KB
  // A buf c: smem + c*16384 (256x64) ; B buf c: smem + 32768 + c*8192 (128x64)
  const int tid = threadIdx.x;
  const int lane = tid & 63;
  const int wid = tid >> 6;        // 0..7
  const int wm = wid >> 1;         // 0..3 (64-row band of 256)
  const int wn = wid & 1;          // 0..1 (64-col half of 128)
  const int quad = lane >> 4, l16 = lane & 15;
  const int swl = l16 & 7;
  const int bm = blockIdx.y * 256, bn = blockIdx.x * 128;
  const int r8 = lane >> 3, s8 = lane & 7;
  const int cst = s8 ^ r8;         // staging chunk swizzle (m&7 == r8)

  fx4 acc[4][4];
#pragma unroll
  for (int i = 0; i < 4; ++i)
#pragma unroll
    for (int j = 0; j < 4; ++j) acc[i][j] = (fx4){0.f, 0.f, 0.f, 0.f};

  const ushort* apA = A + (size_t)(bm + wid * 8 + r8) * K + cst * 8;
  const ushort* apB = Bt + (size_t)(bn + wid * 8 + r8) * K + cst * 8;
  const int dofs = (wid * 8) * 64;

  // ---- prologue: stage tile 0 into buf 0 (counted wait in-loop) ----
#pragma unroll
  for (int s = 0; s < 4; ++s)
    gld_lds16(apA + (size_t)(s * 64) * K, smem + dofs + s * 4096);
#pragma unroll
  for (int s = 0; s < 2; ++s)
    gld_lds16(apB + (size_t)(s * 64) * K, smem + 32768 + dofs + s * 4096);

  const int NT = K >> 6;
  for (int kt = 0; kt < NT; ++kt) {
    const int cur = kt & 1, nxt = cur ^ 1;
    const ushort* As = smem + cur * 16384;
    const ushort* Bs = smem + 32768 + cur * 8192;
    const bool pf = (kt + 1 < NT);
    const ushort* sa = apA + (kt + 1) * 64;
    const ushort* sb = apB + (kt + 1) * 64;
    ushort* dA = smem + nxt * 16384 + dofs;
    ushort* dB = smem + 32768 + nxt * 8192 + dofs;

#pragma unroll
    for (int ks = 0; ks < 2; ++ks) {
      // ---- stage half of kt+1's tile (3 DMAs) into the freed buffer ----
      if (pf) {
        if (ks == 0) {
          gld_lds16(sa, dA);
          gld_lds16(sa + (size_t)64 * K, dA + 4096);
          gld_lds16(sa + (size_t)128 * K, dA + 8192);
        } else {
          gld_lds16(sa + (size_t)192 * K, dA + 12288);
          gld_lds16(sb, dB);
          gld_lds16(sb + (size_t)64 * K, dB + 4096);
        }
      }
      if (ks == 0) {
        if (pf) asm volatile("s_waitcnt vmcnt(3)" ::: "memory");
        else    asm volatile("s_waitcnt vmcnt(0)" ::: "memory");
        __builtin_amdgcn_s_barrier();
      }
      const int so = (((ks * 4 + quad) ^ swl) << 3);
      bs8 af[4], bf[4];
#pragma unroll
      for (int mt = 0; mt < 4; ++mt) {
        int m = wm * 64 + mt * 16 + l16;
        af[mt] = *(const bs8*)(As + m * 64 + so);
      }
#pragma unroll
      for (int nt = 0; nt < 4; ++nt) {
        int n = wn * 64 + nt * 16 + l16;
        bf[nt] = *(const bs8*)(Bs + n * 64 + so);
      }
      __builtin_amdgcn_s_setprio(1);
#pragma unroll
      for (int mt = 0; mt < 4; ++mt)
#pragma unroll
        for (int nt = 0; nt < 4; ++nt)
          acc[mt][nt] = __builtin_amdgcn_mfma_f32_16x16x32_bf16(af[mt], bf[nt],
                                                                acc[mt][nt], 0, 0, 0);
      __builtin_amdgcn_s_setprio(0);
      if (ks == 1)  // my reads of buf cur complete before licensing overwrite
        asm volatile("s_waitcnt lgkmcnt(0)" ::: "memory");
      __builtin_amdgcn_s_barrier();  // phase lock / tile-end licensing
    }
  }

  // ---- epilogue: bf16 LDS round-trip [256][136] (overlays buffers) ----
  for (int mt = 0; mt < 4; ++mt)
    for (int nt = 0; nt < 4; ++nt)
      for (int r = 0; r < 4; ++r) {
        int row = wm * 64 + mt * 16 + quad * 4 + r;   // 0..255
        int col = wn * 64 + nt * 16 + l16;            // 0..127
        smem[row * EPI_STRIDE + col] = f2b(acc[mt][nt][r]);
      }
  __syncthreads();
  const int rsel = tid >> 4;   // 0..31
  const int csel = tid & 15;   // 16B chunk
  for (int ii = 0; ii < 8; ++ii) {
    int row = ii * 32 + rsel;
    us8 chunk = *(const us8*)(smem + row * EPI_STRIDE + csel * 8);
    int row_g = bm + row;
    int colc = bn + csel * 8;
    float4 lo = {b2f(chunk[0]), b2f(chunk[1]), b2f(chunk[2]), b2f(chunk[3])};
    float4 hi = {b2f(chunk[4]), b2f(chunk[5]), b2f(chunk[6]), b2f(chunk[7])};
    *(float4*)(Cout + (size_t)row_g * N + colc) = lo;
    *(float4*)(Cout + (size_t)row_g * N + colc + 4) = hi;
  }
}

// ---------------- fused causal WGQA attention, 8-wave blocks ----------------
// Verbatim proven 70.5 us version. Ledger: 32q/wave (r2) concurrency-bound;
// V-from-L2 (r3) latency-bound; split-key partials (r5) VGPR spill. Local opt.
__global__ __launch_bounds__(512, 4) void attn_kernel(const ushort* __restrict__ qb,
                                                      const ushort* __restrict__ kb,
                                                      const ushort* __restrict__ vt,
                                                      ushort* __restrict__ yb,
                                                      const float* __restrict__ wlog) {
  __shared__ alignas(16) ushort Ks[2][64 * 128];   // [buf][key][d], chunk-swizzled
  __shared__ alignas(16) ushort Vs[2][128 * 64];   // [buf][d][key], chunk-swizzled
  __shared__ alignas(16) ushort Ps[128 * 64];      // [q][key], chunk-XOR swizzled

  const int bid = blockIdx.x;
  const int qt = (bid & 256) ? (bid & 15) : 15 - (bid & 15);
  const int h = (bid >> 4) & 15;
  const int b = bid >> 8;
  const int g = h >> 2;
  const int tid = threadIdx.x;
  const int lane = tid & 63;
  const int wid = tid >> 6;        // 0..7
  const int quad = lane >> 4;
  const int l16 = lane & 15;
  const int qw = qt * 128 + wid * 16;   // wave's first query

  const float scale = wlog[g] * 0.08838834764831845f;  // 1/sqrt(128)
  const float sc2 = scale * 1.4426950408889634f;       // * log2(e)

  const ushort* kbase = kb + (size_t)(b * KVH + g) * TT * HD;
  const ushort* vbase = vt + (size_t)(b * KVH + g) * HD * TT;

  // persistent staging pointers; each thread stages 2 K-slots + 2 V-slots
  const ushort* kp;
  const ushort* vp;
  {
    int keyr = wid * 4 + (lane >> 4);          // 0..31
    int si = lane & 15;
    int ck = (si & 8) | ((si ^ keyr) & 7);
    kp = kbase + (size_t)keyr * HD + ck * 8;
    int dr = wid * 8 + (lane >> 3);            // 0..63
    int s8 = lane & 7;
    int cv = s8 ^ (dr & 7);
    vp = vbase + (size_t)dr * TT + cv * 8;
  }

  // ---- prologue: stage tile 0 into buffer 0 (DMA runs under Q-load) ----
  gld_lds16(kp, &Ks[0][wid * 512]);
  gld_lds16(kp + 32 * HD, &Ks[0][4096 + wid * 512]);
  gld_lds16(vp, &Vs[0][wid * 512]);
  gld_lds16(vp + 64 * TT, &Vs[0][4096 + wid * 512]);
  kp += 64 * HD;
  vp += 64;

  // Q fragments in registers (B-operand of S^T = K * Q^T)
  bs8 qf[4];
  {
    int q = qw + l16;
    const ushort* qrow = qb + ((size_t)(b * TT + q)) * DM + h * HD;
#pragma unroll
    for (int ks = 0; ks < 4; ++ks)
      qf[ks] = *(const bs8*)(qrow + ks * 32 + quad * 8);
  }

  float m_i = -INFINITY;  // running max of RAW logits
  float l_i = 0.f;
  fx4 o[8];
#pragma unroll
  for (int i = 0; i < 8; ++i) o[i] = (fx4){0.f, 0.f, 0.f, 0.f};

  const int jmax = 2 * qt + 1;
  for (int j = 0; j <= jmax; ++j) {
    const int cur = j & 1;
    // ---- issue NEXT tile's DMAs first, then wait only for tile j ----
    if (j < jmax) {
      const int nxt = cur ^ 1;
      gld_lds16(kp, &Ks[nxt][wid * 512]);
      gld_lds16(kp + 32 * HD, &Ks[nxt][4096 + wid * 512]);
      gld_lds16(vp, &Vs[nxt][wid * 512]);
      gld_lds16(vp + 64 * TT, &Vs[nxt][4096 + wid * 512]);
      kp += 64 * HD;
      vp += 64;
      asm volatile("s_waitcnt vmcnt(4)" ::: "memory");  // tile j done, j+1 in flight
    } else {
      asm volatile("s_waitcnt vmcnt(0)" ::: "memory");
    }
    __builtin_amdgcn_s_barrier();

    if (j * 64 <= qw + 15) {  // wave has at least one unmasked key
      const ushort* Kc = Ks[cur];
      const ushort* Vc = Vs[cur];
      // ---- S^T = K * Q^T  (64 keys x 16 queries), fp32 acc ----
      fx4 s[4];
#pragma unroll
      for (int mt = 0; mt < 4; ++mt) s[mt] = (fx4){0.f, 0.f, 0.f, 0.f};
      __builtin_amdgcn_s_setprio(1);
#pragma unroll
      for (int mt = 0; mt < 4; ++mt) {
        bs8 a[4];
        int key = mt * 16 + l16;
#pragma unroll
        for (int ks = 0; ks < 4; ++ks) {
          int c = ks * 4 + quad;
          int slot = (c & 8) | ((c ^ key) & 7);
          a[ks] = *(const bs8*)(Kc + key * 128 + slot * 8);
        }
#pragma unroll
        for (int ks = 0; ks < 4; ++ks)
          s[mt] = __builtin_amdgcn_mfma_f32_16x16x32_bf16(a[ks], qf[ks],
                                                          s[mt], 0, 0, 0);
      }
      __builtin_amdgcn_s_setprio(0);

      // ---- causal mask: needed iff tile max key > wave min query ----
      const int q = qw + l16;
      if (j * 64 + 63 > qw) {
#pragma unroll
        for (int mt = 0; mt < 4; ++mt)
#pragma unroll
          for (int r = 0; r < 4; ++r) {
            int key = j * 64 + mt * 16 + quad * 4 + r;
            if (key > q) s[mt][r] = -1e30f;
          }
      }
      float mx = s[0][0];
#pragma unroll
      for (int mt = 0; mt < 4; ++mt)
#pragma unroll
        for (int r = 0; r < 4; ++r) mx = fmaxf(mx, s[mt][r]);
      mx = fmaxf(mx, __shfl_xor(mx, 16));
      mx = fmaxf(mx, __shfl_xor(mx, 32));

      // ---- defer-max: only rescale when the max actually grows (>8 scaled) ----
      if (!__all((mx - m_i) * scale <= 8.0f)) {
        float m_new = fmaxf(m_i, mx);
        float alpha = EXP2((m_i - m_new) * sc2);
        l_i *= alpha;
#pragma unroll
        for (int dmt = 0; dmt < 8; ++dmt)
#pragma unroll
          for (int r = 0; r < 4; ++r) o[dmt][r] *= alpha;
        m_i = m_new;
      }
      float negb = -m_i * sc2;
      float sum = 0.f;
#pragma unroll
      for (int mt = 0; mt < 4; ++mt)
#pragma unroll
        for (int r = 0; r < 4; ++r) {
          float pv = EXP2(fmaf(s[mt][r], sc2, negb));
          s[mt][r] = pv;
          sum += pv;
        }
      sum += __shfl_xor(sum, 16);
      sum += __shfl_xor(sum, 32);
      l_i += sum;

      // P (bf16) to LDS, [q][key] stride 64 with chunk-XOR swizzle;
      // wave touches only its own 16 rows -> no barrier needed
      int qrow = wid * 16 + l16;
      int sw = l16 & 7;
#pragma unroll
      for (int mt = 0; mt < 4; ++mt) {
        us4 pw = {f2b(s[mt][0]), f2b(s[mt][1]), f2b(s[mt][2]), f2b(s[mt][3])};
        int chunk = mt * 2 + (quad >> 1);
        *(us4*)(Ps + qrow * 64 + ((chunk ^ sw) << 3) + ((quad & 1) << 2)) = pw;
      }

      // ---- O^T += V^T * P^T  (no barrier: wave reads only its own P rows) ----
#pragma unroll
      for (int ks = 0; ks < 2; ++ks) {
        bs8 pb = *(const bs8*)(Ps + qrow * 64 + (((ks * 4 + quad) ^ sw) << 3));
        __builtin_amdgcn_s_setprio(1);
#pragma unroll
        for (int dmt = 0; dmt < 8; ++dmt) {
          int d = dmt * 16 + l16;
          int c = ks * 4 + quad;
          int slot = c ^ (d & 7);
          bs8 va = *(const bs8*)(Vc + d * 64 + slot * 8);
          o[dmt] = __builtin_amdgcn_mfma_f32_16x16x32_bf16(va, pb, o[dmt], 0, 0, 0);
        }
        __builtin_amdgcn_s_setprio(0);
      }
    }
    // all my LDS reads of buf[cur] must be complete before signaling; the
    // barrier then licenses other waves' DMAs for tile j+2 to overwrite it
    asm volatile("s_waitcnt lgkmcnt(0)" ::: "memory");
    __builtin_amdgcn_s_barrier();
  }

  // ---- epilogue: normalize and write y (bf16, [b][t][h*128+d]) ----
  {
    float inv = 1.0f / l_i;
    int q = qw + l16;
    ushort* yrow = yb + ((size_t)(b * TT + q)) * DM + h * HD;
#pragma unroll
    for (int dmt = 0; dmt < 8; ++dmt) {
      us4 w = {f2b(o[dmt][0] * inv), f2b(o[dmt][1] * inv),
               f2b(o[dmt][2] * inv), f2b(o[dmt][3] * inv)};
      *(us4*)(yrow + dmt * 16 + quad * 4) = w;
    }
  }
}

// ---------------- launch ----------------
extern "C" void kernel_launch(void* const* d_in, const int* in_sizes, int n_in,
                              void* d_out, int out_size, void* d_ws, size_t ws_size,
                              hipStream_t stream) {
  const float* x = (const float*)d_in[0];
  // d_in[1] = attn_mask: ignored (exact causal mask computed analytically)
  const float* Wq = (const float*)d_in[2];
  const float* Wk = (const float*)d_in[3];
  const float* Wv = (const float*)d_in[4];
  const float* Wo = (const float*)d_in[5];
  const float* wlog = (const float*)d_in[6];
  // d_in[7] = weight_values: unused by the reference

  char* ws = (char*)d_ws;
  ushort* xb = (ushort*)ws;     ws += (size_t)4096 * 2048 * 2;
  ushort* Wqkvt = (ushort*)ws;  ws += (size_t)3072 * 2048 * 2;
  ushort* Wot = (ushort*)ws;    ws += (size_t)2048 * 2048 * 2;
  ushort* qbuf = (ushort*)ws;   ws += (size_t)4096 * 2048 * 2;
  ushort* kbuf = (ushort*)ws;   ws += (size_t)2 * KVH * 2048 * 128 * 2;
  ushort* vbuf = (ushort*)ws;   ws += (size_t)2 * KVH * 2048 * 128 * 2;
  ushort* ybuf = (ushort*)ws;   ws += (size_t)4096 * 2048 * 2;

  prep_kernel<<<dim3(96, 64, 3), dim3(32, 8), 0, stream>>>(
      x, Wq, Wk, Wv, Wo, xb, Wqkvt, Wot);
  gemm_qkv<<<dim3(12, 16), 512, 0, stream>>>(xb, Wqkvt, qbuf, kbuf, vbuf, 2048);
  attn_kernel<<<512, 512, 0, stream>>>(qbuf, kbuf, vbuf, ybuf, wlog);
  gemm_out<<<dim3(16, 16), 512, 0, stream>>>(ybuf, Wot, (float*)d_out, 2048, 2048);
}

// Round 15
// 282.615 us; speedup vs baseline: 1.0746x; 1.0404x over previous
//
#include <hip/hip_runtime.h>
#include <hip/hip_bf16.h>

#define TT 2048
#define DM 2048
#define NH 16
#define KVH 4
#define HD 128

typedef __attribute__((ext_vector_type(8))) short bs8;
typedef __attribute__((ext_vector_type(4))) float fx4;
typedef __attribute__((ext_vector_type(4))) unsigned short us4;
typedef __attribute__((ext_vector_type(8))) unsigned short us8;

#if __has_builtin(__builtin_amdgcn_exp2f)
#define EXP2(x) __builtin_amdgcn_exp2f(x)
#else
#define EXP2(x) exp2f(x)
#endif

__device__ inline unsigned short f2b(float f) {
  __hip_bfloat16 h = __float2bfloat16(f);
  return *reinterpret_cast<unsigned short*>(&h);
}

__device__ inline float b2f(unsigned short u) {
  unsigned int v = ((unsigned int)u) << 16;
  return *reinterpret_cast<float*>(&v);
}

__device__ inline void gld_lds16(const ushort* g, ushort* l) {
  __builtin_amdgcn_global_load_lds(
      (const __attribute__((address_space(1))) void*)g,
      (__attribute__((address_space(3))) void*)l,
      16, 0, 0);
}

// ---------------- prep: weight transposes + x cast, one dispatch ----------------
// z=0: Wqkvt[3072][2048] from Wq|Wk|Wv   z=1: Wot[2048][2048] from Wo
// z=2: x fp32 -> bf16 cast (linear)
__global__ __launch_bounds__(256) void prep_kernel(
    const float* __restrict__ x, const float* __restrict__ Wq,
    const float* __restrict__ Wk, const float* __restrict__ Wv,
    const float* __restrict__ Wo, ushort* __restrict__ xb,
    ushort* __restrict__ Wqkvt, ushort* __restrict__ Wot) {
  int tx = threadIdx.x, ty = threadIdx.y;  // block (32,8)
  if (blockIdx.z == 2) {
    int lin = (blockIdx.y * 96 + blockIdx.x) * 256 + ty * 32 + tx;
#pragma unroll
    for (int it = 0; it < 2; ++it) {
      int i = lin + it * (6144 * 256);
      if (i < (TT * 2 * DM) / 4) {
        float4 v = ((const float4*)x)[i];
        us4 o = {f2b(v.x), f2b(v.y), f2b(v.z), f2b(v.w)};
        ((us4*)xb)[i] = o;
      }
    }
    return;
  }
  __shared__ float t[32][33];
  int n0 = blockIdx.x * 32, k0 = blockIdx.y * 32;
  if (blockIdx.z == 0) {
    const float* src;
    int srcN, col0;
    if (n0 < 2048) { src = Wq; srcN = 2048; col0 = n0; }
    else if (n0 < 2560) { src = Wk; srcN = 512; col0 = n0 - 2048; }
    else { src = Wv; srcN = 512; col0 = n0 - 2560; }
    for (int jj = 0; jj < 4; ++jj)
      t[ty + jj * 8][tx] = src[(size_t)(k0 + ty + jj * 8) * srcN + col0 + tx];
    __syncthreads();
    for (int jj = 0; jj < 4; ++jj)
      Wqkvt[(size_t)(n0 + ty + jj * 8) * 2048 + k0 + tx] = f2b(t[tx][ty + jj * 8]);
  } else {
    if (n0 >= 2048) return;
    for (int jj = 0; jj < 4; ++jj)
      t[ty + jj * 8][tx] = Wo[(size_t)(k0 + ty + jj * 8) * 2048 + n0 + tx];
    __syncthreads();
    for (int jj = 0; jj < 4; ++jj)
      Wot[(size_t)(n0 + ty + jj * 8) * 2048 + k0 + tx] = f2b(t[tx][ty + jj * 8]);
  }
}

// ---------------- fused QKV GEMM: [4096 x 3072] = xb * Wqkvt^T ----------------
// ROUND-15: 256x192 tile -> grid 16x16 = 256 blocks = 100% CU fill (the 256^2
// tile was stuck at 192/256 = 75%). Proven 4-phase counted-vmcnt interleave
// kept verbatim: 7 DMAs/thread/K-step spread 2/2/2/1 across phases, vmcnt(2)
// at p0 drains exactly tile kt. 8 waves (2M x 4N), wave owns 128x48,
// acc[8][3] = 96 VGPR. LDS 112 KB dbuf (1 block/CU, 2 waves/SIMD — same
// occupancy as before). Epilogue: three 64-col slabs (q/k/v boundaries 2048,
// 2560 are multiples of 64 so each slab is uniform); slab <- col-tile index
// ct = wn*3+nt (bijective over 12); q/k slabs row-major [256][72], v slabs
// transposed [64][264]; compile-time vector indices only.
#define EPI_STRIDE 136  // shorts (legacy, gemm_out)
#define QK_STRIDE 72    // shorts; 144 B rows, 16B-aligned
#define VT_STRIDE 264   // shorts; 528 B rows, 16B-aligned
__global__ __launch_bounds__(512, 2) void gemm_qkv(const ushort* __restrict__ A,
                                                   const ushort* __restrict__ Bt,
                                                   ushort* __restrict__ qo,
                                                   ushort* __restrict__ ko,
                                                   ushort* __restrict__ vo,
                                                   int K) {
  __shared__ alignas(16) ushort smem[57344];  // 112 KB
  // A buf c: smem + c*16384 (256x64) ; B buf c: smem + 32768 + c*12288 (192x64)
  const int tid = threadIdx.x;
  const int lane = tid & 63;
  const int wid = tid >> 6;        // 0..7
  const int wm = wid >> 2;         // 0..1  (output row half, 128 rows)
  const int wn = wid & 3;          // 0..3  (output col quarter, 48 cols)
  const int quad = lane >> 4, l16 = lane & 15;
  const int swl = l16 & 7;
  const int bm = blockIdx.y * 256, bn = blockIdx.x * 192;
  const int r8 = lane >> 3, s8 = lane & 7;
  const int cst = s8 ^ r8;         // staging chunk swizzle (row&7 == r8)

  fx4 acc[8][3];
#pragma unroll
  for (int i = 0; i < 8; ++i)
#pragma unroll
    for (int j = 0; j < 3; ++j) acc[i][j] = (fx4){0.f, 0.f, 0.f, 0.f};

  // per-thread staging base pointers (stripe s adds s*64 rows)
  const ushort* apA = A + (size_t)(bm + wid * 8 + r8) * K + cst * 8;
  const ushort* apB = Bt + (size_t)(bn + wid * 8 + r8) * K + cst * 8;
  const int dofs = (wid * 8) * 64;  // LDS dest offset within buffer

  // ---- prologue: stage tile 0 into buf 0 (counted wait in-loop) ----
#pragma unroll
  for (int s = 0; s < 4; ++s)
    gld_lds16(apA + (size_t)(s * 64) * K, smem + dofs + s * 4096);
#pragma unroll
  for (int s = 0; s < 3; ++s)
    gld_lds16(apB + (size_t)(s * 64) * K, smem + 32768 + dofs + s * 4096);

  const int NT = K >> 6;
  for (int kt = 0; kt < NT; ++kt) {
    const int cur = kt & 1, nxt = cur ^ 1;
    const ushort* As = smem + cur * 16384;
    const ushort* Bs = smem + 32768 + cur * 12288;
    const bool pf = (kt + 1 < NT);
    const ushort* sa = apA + (kt + 1) * 64;
    const ushort* sb = apB + (kt + 1) * 64;
    ushort* dA = smem + nxt * 16384 + dofs;
    ushort* dB = smem + 32768 + nxt * 12288 + dofs;

#pragma unroll
    for (int p = 0; p < 4; ++p) {
      // ---- stage part of kt+1 (2/2/2/1 DMAs) into the freed buffer ----
      if (pf) {
        if (p == 0) {
          gld_lds16(sa, dA);
          gld_lds16(sa + (size_t)64 * K, dA + 4096);
        } else if (p == 1) {
          gld_lds16(sa + (size_t)128 * K, dA + 8192);
          gld_lds16(sa + (size_t)192 * K, dA + 12288);
        } else if (p == 2) {
          gld_lds16(sb, dB);
          gld_lds16(sb + (size_t)64 * K, dB + 4096);
        } else {
          gld_lds16(sb + (size_t)128 * K, dB + 8192);
        }
      }
      if (p == 0) {
        // tile kt's 7 loads (oldest outstanding) landed; kt+1's stay in flight
        if (pf) asm volatile("s_waitcnt vmcnt(2)" ::: "memory");
        else    asm volatile("s_waitcnt vmcnt(0)" ::: "memory");
        __builtin_amdgcn_s_barrier();
      }
      const int ks = p >> 1, mh = p & 1;
      const int so = (((ks * 4 + quad) ^ swl) << 3);  // swizzled 16B slot
      bs8 bf[3], af[4];
#pragma unroll
      for (int nt = 0; nt < 3; ++nt) {
        int n = wn * 48 + nt * 16 + l16;
        bf[nt] = *(const bs8*)(Bs + n * 64 + so);
      }
#pragma unroll
      for (int i = 0; i < 4; ++i) {
        int m = wm * 128 + (mh * 4 + i) * 16 + l16;
        af[i] = *(const bs8*)(As + m * 64 + so);
      }
      __builtin_amdgcn_s_setprio(1);
#pragma unroll
      for (int i = 0; i < 4; ++i)
#pragma unroll
        for (int nt = 0; nt < 3; ++nt)
          acc[mh * 4 + i][nt] = __builtin_amdgcn_mfma_f32_16x16x32_bf16(
              af[i], bf[nt], acc[mh * 4 + i][nt], 0, 0, 0);
      __builtin_amdgcn_s_setprio(0);
      if (p == 3)  // my reads of buf cur complete before licensing overwrite
        asm volatile("s_waitcnt lgkmcnt(0)" ::: "memory");
      __builtin_amdgcn_s_barrier();  // phase lock / tile-end licensing
    }
  }

  // ---- epilogue: three 64-col slabs, each uniformly q, k, or v ----
  const int bb = bm >> 11;       // batch (256-row tile never straddles)
  const int t0 = bm & 2047;
#pragma unroll
  for (int sl = 0; sl < 3; ++sl) {
    const int gcol0 = bn + sl * 64;
    const bool isv = (gcol0 >= 2560);
    // write phase: waves owning col-tiles of this slab write to LDS
#pragma unroll
    for (int nt = 0; nt < 3; ++nt) {
      int ct = wn * 3 + nt;
      if ((ct >> 2) == sl) {
        int colw = (ct & 3) * 16 + l16;   // 0..63 within slab
        if (isv) {
#pragma unroll
          for (int mt = 0; mt < 8; ++mt)
#pragma unroll
            for (int r = 0; r < 4; ++r) {
              int row = wm * 128 + mt * 16 + quad * 4 + r;   // token 0..255
              smem[colw * VT_STRIDE + row] = f2b(acc[mt][nt][r]);
            }
        } else {
#pragma unroll
          for (int mt = 0; mt < 8; ++mt)
#pragma unroll
            for (int r = 0; r < 4; ++r) {
              int row = wm * 128 + mt * 16 + quad * 4 + r;
              smem[row * QK_STRIDE + colw] = f2b(acc[mt][nt][r]);
            }
        }
      }
    }
    __builtin_amdgcn_s_barrier();
    if (isv) {
      const int tc = tid & 31;     // token chunk (8 tokens)
      const int drsel = tid >> 5;  // 0..15
      for (int it = 0; it < 4; ++it) {
        int dl = it * 16 + drsel;                      // 0..63 within slab
        us8 chunk = *(const us8*)(smem + dl * VT_STRIDE + tc * 8);
        int vc = gcol0 - 2560 + dl;                    // 0..511
        int gg = vc >> 7, dd = vc & 127;
        *(us8*)(vo + ((size_t)(bb * KVH + gg) * HD + dd) * TT + t0 + tc * 8) = chunk;
      }
    } else {
      const int rsel = tid >> 3;   // 0..63
      const int csel = tid & 7;    // 16B chunk within 64-col slab
      for (int ii = 0; ii < 4; ++ii) {
        int row = ii * 64 + rsel;
        us8 chunk = *(const us8*)(smem + row * QK_STRIDE + csel * 8);
        int row_g = bm + row;
        int colc = gcol0 + csel * 8;
        if (colc < 2048) {
          *(us8*)(qo + (size_t)row_g * 2048 + colc) = chunk;
        } else {
          int t = row_g & 2047;
          int kc = colc - 2048;
          int gg = kc >> 7, d = kc & 127;
          *(us8*)(ko + ((size_t)(bb * KVH + gg) * TT + t) * HD + d) = chunk;
        }
      }
    }
    __builtin_amdgcn_s_barrier();
  }
}

// ---------------- output-projection GEMM: fp32 out ----------------
// r14-proven: 256x128 tile, 100% fill, 2-phase ks-split counted-vmcnt loop.
__global__ __launch_bounds__(512, 2) void gemm_out(const ushort* __restrict__ A,
                                                   const ushort* __restrict__ Bt,
                                                   float* __restrict__ Cout,
                                                   int N, int K) {
  __shared__ alignas(16) ushort smem[49152];  // 96 KB
  // A buf c: smem + c*16384 (256x64) ; B buf c: smem + 32768 + c*8192 (128x64)
  const int tid = threadIdx.x;
  const int lane = tid & 63;
  const int wid = tid >> 6;        // 0..7
  const int wm = wid >> 1;         // 0..3 (64-row band of 256)
  const int wn = wid & 1;          // 0..1 (64-col half of 128)
  const int quad = lane >> 4, l16 = lane & 15;
  const int swl = l16 & 7;
  const int bm = blockIdx.y * 256, bn = blockIdx.x * 128;
  const int r8 = lane >> 3, s8 = lane & 7;
  const int cst = s8 ^ r8;         // staging chunk swizzle (m&7 == r8)

  fx4 acc[4][4];
#pragma unroll
  for (int i = 0; i < 4; ++i)
#pragma unroll
    for (int j = 0; j < 4; ++j) acc[i][j] = (fx4){0.f, 0.f, 0.f, 0.f};

  const ushort* apA = A + (size_t)(bm + wid * 8 + r8) * K + cst * 8;
  const ushort* apB = Bt + (size_t)(bn + wid * 8 + r8) * K + cst * 8;
  const int dofs = (wid * 8) * 64;

  // ---- prologue: stage tile 0 into buf 0 (counted wait in-loop) ----
#pragma unroll
  for (int s = 0; s < 4; ++s)
    gld_lds16(apA + (size_t)(s * 64) * K, smem + dofs + s * 4096);
#pragma unroll
  for (int s = 0; s < 2; ++s)
    gld_lds16(apB + (size_t)(s * 64) * K, smem + 32768 + dofs + s * 4096);

  const int NT = K >> 6;
  for (int kt = 0; kt < NT; ++kt) {
    const int cur = kt & 1, nxt = cur ^ 1;
    const ushort* As = smem + cur * 16384;
    const ushort* Bs = smem + 32768 + cur * 8192;
    const bool pf = (kt + 1 < NT);
    const ushort* sa = apA + (kt + 1) * 64;
    const ushort* sb = apB + (kt + 1) * 64;
    ushort* dA = smem + nxt * 16384 + dofs;
    ushort* dB = smem + 32768 + nxt * 8192 + dofs;

#pragma unroll
    for (int ks = 0; ks < 2; ++ks) {
      // ---- stage half of kt+1's tile (3 DMAs) into the freed buffer ----
      if (pf) {
        if (ks == 0) {
          gld_lds16(sa, dA);
          gld_lds16(sa + (size_t)64 * K, dA + 4096);
          gld_lds16(sa + (size_t)128 * K, dA + 8192);
        } else {
          gld_lds16(sa + (size_t)192 * K, dA + 12288);
          gld_lds16(sb, dB);
          gld_lds16(sb + (size_t)64 * K, dB + 4096);
        }
      }
      if (ks == 0) {
        if (pf) asm volatile("s_waitcnt vmcnt(3)" ::: "memory");
        else    asm volatile("s_waitcnt vmcnt(0)" ::: "memory");
        __builtin_amdgcn_s_barrier();
      }
      const int so = (((ks * 4 + quad) ^ swl) << 3);
      bs8 af[4], bf[4];
#pragma unroll
      for (int mt = 0; mt < 4; ++mt) {
        int m = wm * 64 + mt * 16 + l16;
        af[mt] = *(const bs8*)(As + m * 64 + so);
      }
#pragma unroll
      for (int nt = 0; nt < 4; ++nt) {
        int n = wn * 64 + nt * 16 + l16;
        bf[nt] = *(const bs8*)(Bs + n * 64 + so);
      }
      __builtin_amdgcn_s_setprio(1);
#pragma unroll
      for (int mt = 0; mt < 4; ++mt)
#pragma unroll
        for (int nt = 0; nt < 4; ++nt)
          acc[mt][nt] = __builtin_amdgcn_mfma_f32_16x16x32_bf16(af[mt], bf[nt],
                                                                acc[mt][nt], 0, 0, 0);
      __builtin_amdgcn_s_setprio(0);
      if (ks == 1)  // my reads of buf cur complete before licensing overwrite
        asm volatile("s_waitcnt lgkmcnt(0)" ::: "memory");
      __builtin_amdgcn_s_barrier();  // phase lock / tile-end licensing
    }
  }

  // ---- epilogue: bf16 LDS round-trip [256][136] (overlays buffers) ----
  for (int mt = 0; mt < 4; ++mt)
    for (int nt = 0; nt < 4; ++nt)
      for (int r = 0; r < 4; ++r) {
        int row = wm * 64 + mt * 16 + quad * 4 + r;   // 0..255
        int col = wn * 64 + nt * 16 + l16;            // 0..127
        smem[row * EPI_STRIDE + col] = f2b(acc[mt][nt][r]);
      }
  __syncthreads();
  const int rsel = tid >> 4;   // 0..31
  const int csel = tid & 15;   // 16B chunk
  for (int ii = 0; ii < 8; ++ii) {
    int row = ii * 32 + rsel;
    us8 chunk = *(const us8*)(smem + row * EPI_STRIDE + csel * 8);
    int row_g = bm + row;
    int colc = bn + csel * 8;
    float4 lo = {b2f(chunk[0]), b2f(chunk[1]), b2f(chunk[2]), b2f(chunk[3])};
    float4 hi = {b2f(chunk[4]), b2f(chunk[5]), b2f(chunk[6]), b2f(chunk[7])};
    *(float4*)(Cout + (size_t)row_g * N + colc) = lo;
    *(float4*)(Cout + (size_t)row_g * N + colc + 4) = hi;
  }
}

// ---------------- fused causal WGQA attention, 8-wave blocks ----------------
// Verbatim proven 70.5 us version. Ledger: 32q/wave (r2) concurrency-bound;
// V-from-L2 (r3) latency-bound; split-key partials (r5) VGPR spill. Local opt.
__global__ __launch_bounds__(512, 4) void attn_kernel(const ushort* __restrict__ qb,
                                                      const ushort* __restrict__ kb,
                                                      const ushort* __restrict__ vt,
                                                      ushort* __restrict__ yb,
                                                      const float* __restrict__ wlog) {
  __shared__ alignas(16) ushort Ks[2][64 * 128];   // [buf][key][d], chunk-swizzled
  __shared__ alignas(16) ushort Vs[2][128 * 64];   // [buf][d][key], chunk-swizzled
  __shared__ alignas(16) ushort Ps[128 * 64];      // [q][key], chunk-XOR swizzled

  const int bid = blockIdx.x;
  const int qt = (bid & 256) ? (bid & 15) : 15 - (bid & 15);
  const int h = (bid >> 4) & 15;
  const int b = bid >> 8;
  const int g = h >> 2;
  const int tid = threadIdx.x;
  const int lane = tid & 63;
  const int wid = tid >> 6;        // 0..7
  const int quad = lane >> 4;
  const int l16 = lane & 15;
  const int qw = qt * 128 + wid * 16;   // wave's first query

  const float scale = wlog[g] * 0.08838834764831845f;  // 1/sqrt(128)
  const float sc2 = scale * 1.4426950408889634f;       // * log2(e)

  const ushort* kbase = kb + (size_t)(b * KVH + g) * TT * HD;
  const ushort* vbase = vt + (size_t)(b * KVH + g) * HD * TT;

  // persistent staging pointers; each thread stages 2 K-slots + 2 V-slots
  const ushort* kp;
  const ushort* vp;
  {
    int keyr = wid * 4 + (lane >> 4);          // 0..31
    int si = lane & 15;
    int ck = (si & 8) | ((si ^ keyr) & 7);
    kp = kbase + (size_t)keyr * HD + ck * 8;
    int dr = wid * 8 + (lane >> 3);            // 0..63
    int s8 = lane & 7;
    int cv = s8 ^ (dr & 7);
    vp = vbase + (size_t)dr * TT + cv * 8;
  }

  // ---- prologue: stage tile 0 into buffer 0 (DMA runs under Q-load) ----
  gld_lds16(kp, &Ks[0][wid * 512]);
  gld_lds16(kp + 32 * HD, &Ks[0][4096 + wid * 512]);
  gld_lds16(vp, &Vs[0][wid * 512]);
  gld_lds16(vp + 64 * TT, &Vs[0][4096 + wid * 512]);
  kp += 64 * HD;
  vp += 64;

  // Q fragments in registers (B-operand of S^T = K * Q^T)
  bs8 qf[4];
  {
    int q = qw + l16;
    const ushort* qrow = qb + ((size_t)(b * TT + q)) * DM + h * HD;
#pragma unroll
    for (int ks = 0; ks < 4; ++ks)
      qf[ks] = *(const bs8*)(qrow + ks * 32 + quad * 8);
  }

  float m_i = -INFINITY;  // running max of RAW logits
  float l_i = 0.f;
  fx4 o[8];
#pragma unroll
  for (int i = 0; i < 8; ++i) o[i] = (fx4){0.f, 0.f, 0.f, 0.f};

  const int jmax = 2 * qt + 1;
  for (int j = 0; j <= jmax; ++j) {
    const int cur = j & 1;
    // ---- issue NEXT tile's DMAs first, then wait only for tile j ----
    if (j < jmax) {
      const int nxt = cur ^ 1;
      gld_lds16(kp, &Ks[nxt][wid * 512]);
      gld_lds16(kp + 32 * HD, &Ks[nxt][4096 + wid * 512]);
      gld_lds16(vp, &Vs[nxt][wid * 512]);
      gld_lds16(vp + 64 * TT, &Vs[nxt][4096 + wid * 512]);
      kp += 64 * HD;
      vp += 64;
      asm volatile("s_waitcnt vmcnt(4)" ::: "memory");  // tile j done, j+1 in flight
    } else {
      asm volatile("s_waitcnt vmcnt(0)" ::: "memory");
    }
    __builtin_amdgcn_s_barrier();

    if (j * 64 <= qw + 15) {  // wave has at least one unmasked key
      const ushort* Kc = Ks[cur];
      const ushort* Vc = Vs[cur];
      // ---- S^T = K * Q^T  (64 keys x 16 queries), fp32 acc ----
      fx4 s[4];
#pragma unroll
      for (int mt = 0; mt < 4; ++mt) s[mt] = (fx4){0.f, 0.f, 0.f, 0.f};
      __builtin_amdgcn_s_setprio(1);
#pragma unroll
      for (int mt = 0; mt < 4; ++mt) {
        bs8 a[4];
        int key = mt * 16 + l16;
#pragma unroll
        for (int ks = 0; ks < 4; ++ks) {
          int c = ks * 4 + quad;
          int slot = (c & 8) | ((c ^ key) & 7);
          a[ks] = *(const bs8*)(Kc + key * 128 + slot * 8);
        }
#pragma unroll
        for (int ks = 0; ks < 4; ++ks)
          s[mt] = __builtin_amdgcn_mfma_f32_16x16x32_bf16(a[ks], qf[ks],
                                                          s[mt], 0, 0, 0);
      }
      __builtin_amdgcn_s_setprio(0);

      // ---- causal mask: needed iff tile max key > wave min query ----
      const int q = qw + l16;
      if (j * 64 + 63 > qw) {
#pragma unroll
        for (int mt = 0; mt < 4; ++mt)
#pragma unroll
          for (int r = 0; r < 4; ++r) {
            int key = j * 64 + mt * 16 + quad * 4 + r;
            if (key > q) s[mt][r] = -1e30f;
          }
      }
      float mx = s[0][0];
#pragma unroll
      for (int mt = 0; mt < 4; ++mt)
#pragma unroll
        for (int r = 0; r < 4; ++r) mx = fmaxf(mx, s[mt][r]);
      mx = fmaxf(mx, __shfl_xor(mx, 16));
      mx = fmaxf(mx, __shfl_xor(mx, 32));

      // ---- defer-max: only rescale when the max actually grows (>8 scaled) ----
      if (!__all((mx - m_i) * scale <= 8.0f)) {
        float m_new = fmaxf(m_i, mx);
        float alpha = EXP2((m_i - m_new) * sc2);
        l_i *= alpha;
#pragma unroll
        for (int dmt = 0; dmt < 8; ++dmt)
#pragma unroll
          for (int r = 0; r < 4; ++r) o[dmt][r] *= alpha;
        m_i = m_new;
      }
      float negb = -m_i * sc2;
      float sum = 0.f;
#pragma unroll
      for (int mt = 0; mt < 4; ++mt)
#pragma unroll
        for (int r = 0; r < 4; ++r) {
          float pv = EXP2(fmaf(s[mt][r], sc2, negb));
          s[mt][r] = pv;
          sum += pv;
        }
      sum += __shfl_xor(sum, 16);
      sum += __shfl_xor(sum, 32);
      l_i += sum;

      // P (bf16) to LDS, [q][key] stride 64 with chunk-XOR swizzle;
      // wave touches only its own 16 rows -> no barrier needed
      int qrow = wid * 16 + l16;
      int sw = l16 & 7;
#pragma unroll
      for (int mt = 0; mt < 4; ++mt) {
        us4 pw = {f2b(s[mt][0]), f2b(s[mt][1]), f2b(s[mt][2]), f2b(s[mt][3])};
        int chunk = mt * 2 + (quad >> 1);
        *(us4*)(Ps + qrow * 64 + ((chunk ^ sw) << 3) + ((quad & 1) << 2)) = pw;
      }

      // ---- O^T += V^T * P^T  (no barrier: wave reads only its own P rows) ----
#pragma unroll
      for (int ks = 0; ks < 2; ++ks) {
        bs8 pb = *(const bs8*)(Ps + qrow * 64 + (((ks * 4 + quad) ^ sw) << 3));
        __builtin_amdgcn_s_setprio(1);
#pragma unroll
        for (int dmt = 0; dmt < 8; ++dmt) {
          int d = dmt * 16 + l16;
          int c = ks * 4 + quad;
          int slot = c ^ (d & 7);
          bs8 va = *(const bs8*)(Vc + d * 64 + slot * 8);
          o[dmt] = __builtin_amdgcn_mfma_f32_16x16x32_bf16(va, pb, o[dmt], 0, 0, 0);
        }
        __builtin_amdgcn_s_setprio(0);
      }
    }
    // all my LDS reads of buf[cur] must be complete before signaling; the
    // barrier then licenses other waves' DMAs for tile j+2 to overwrite it
    asm volatile("s_waitcnt lgkmcnt(0)" ::: "memory");
    __builtin_amdgcn_s_barrier();
  }

  // ---- epilogue: normalize and write y (bf16, [b][t][h*128+d]) ----
  {
    float inv = 1.0f / l_i;
    int q = qw + l16;
    ushort* yrow = yb + ((size_t)(b * TT + q)) * DM + h * HD;
#pragma unroll
    for (int dmt = 0; dmt < 8; ++dmt) {
      us4 w = {f2b(o[dmt][0] * inv), f2b(o[dmt][1] * inv),
               f2b(o[dmt][2] * inv), f2b(o[dmt][3] * inv)};
      *(us4*)(yrow + dmt * 16 + quad * 4) = w;
    }
  }
}

// ---------------- launch ----------------
extern "C" void kernel_launch(void* const* d_in, const int* in_sizes, int n_in,
                              void* d_out, int out_size, void* d_ws, size_t ws_size,
                              hipStream_t stream) {
  const float* x = (const float*)d_in[0];
  // d_in[1] = attn_mask: ignored (exact causal mask computed analytically)
  const float* Wq = (const float*)d_in[2];
  const float* Wk = (const float*)d_in[3];
  const float* Wv = (const float*)d_in[4];
  const float* Wo = (const float*)d_in[5];
  const float* wlog = (const float*)d_in[6];
  // d_in[7] = weight_values: unused by the reference

  char* ws = (char*)d_ws;
  ushort* xb = (ushort*)ws;     ws += (size_t)4096 * 2048 * 2;
  ushort* Wqkvt = (ushort*)ws;  ws += (size_t)3072 * 2048 * 2;
  ushort* Wot = (ushort*)ws;    ws += (size_t)2048 * 2048 * 2;
  ushort* qbuf = (ushort*)ws;   ws += (size_t)4096 * 2048 * 2;
  ushort* kbuf = (ushort*)ws;   ws += (size_t)2 * KVH * 2048 * 128 * 2;
  ushort* vbuf = (ushort*)ws;   ws += (size_t)2 * KVH * 2048 * 128 * 2;
  ushort* ybuf = (ushort*)ws;   ws += (size_t)4096 * 2048 * 2;

  prep_kernel<<<dim3(96, 64, 3), dim3(32, 8), 0, stream>>>(
      x, Wq, Wk, Wv, Wo, xb, Wqkvt, Wot);
  gemm_qkv<<<dim3(16, 16), 512, 0, stream>>>(xb, Wqkvt, qbuf, kbuf, vbuf, 2048);
  attn_kernel<<<512, 512, 0, stream>>>(qbuf, kbuf, vbuf, ybuf, wlog);
  gemm_out<<<dim3(16, 16), 512, 0, stream>>>(ybuf, Wot, (float*)d_out, 2048, 2048);
}